// Round 4
// baseline (4737.648 us; speedup 1.0000x reference)
//
#include <hip/hip_runtime.h>
#include <cstdint>
#include <cstddef>

#define T_DIM 128
#define B_DIM 256
#define F_DIM 512
#define H_DIM 1024
#define G_DIM 4096   // 4*H

typedef unsigned short u16;
typedef unsigned short u16x8 __attribute__((ext_vector_type(8)));
typedef unsigned short u16x4 __attribute__((ext_vector_type(4)));
typedef __bf16 bf16x8 __attribute__((ext_vector_type(8)));
typedef float f32x4 __attribute__((ext_vector_type(4)));

__device__ __forceinline__ float bf2f(u16 u) {
    union { unsigned v; float f; } x; x.v = ((unsigned)u) << 16; return x.f;
}
__device__ __forceinline__ u16 f2bf(float f) {
    union { float f; unsigned v; } x; x.f = f;
    return (u16)((x.v + 0x7fffu + ((x.v >> 16) & 1u)) >> 16);
}

__device__ __forceinline__ f32x4 mfma16(u16x8 a, u16x8 b, f32x4 c) {
    return __builtin_amdgcn_mfma_f32_16x16x32_bf16(
        __builtin_bit_cast(bf16x8, a), __builtin_bit_cast(bf16x8, b), c, 0, 0, 0);
}

__device__ __forceinline__ void gl_lds16(const void* g, void* s) {
    __builtin_amdgcn_global_load_lds(
        (const __attribute__((address_space(1))) void*)g,
        (__attribute__((address_space(3))) void*)s, 16, 0, 0);
}

__device__ __forceinline__ float sigm(float x) { return 1.0f / (1.0f + __expf(-x)); }
__device__ __forceinline__ float tanh_fast(float x) {
    float e = __expf(2.0f * x);
    return 1.0f - 2.0f / (e + 1.0f);
}

// ---------------------------------------------------------------------------
// GEMM: C[M,N] = epi(A[M,K] * B[N,K]^T + bias), bf16 in/out, f32 accum.
// 128x128 tile, BK=64, 4 waves (2x2). Epilogue bounces C through LDS so global
// stores are 16B/lane coalesced (R2 showed 3.5x HBM write amplification).
// ---------------------------------------------------------------------------
template <int EPI>
__global__ __launch_bounds__(256) void gemm_bt128(
    const u16* __restrict__ A, const u16* __restrict__ B,
    const float* __restrict__ bias, u16* __restrict__ C, int K, int N) {
    __shared__ __align__(16) u16 smem[128 * 136];  // staging 16384 u16; epi 128x136
    u16* lA = smem;
    u16* lB = smem + 8192;
    const int lane = threadIdx.x & 63;
    const int wave = threadIdx.x >> 6;
    const int wr = wave >> 1, wc = wave & 1;
    const int bm = blockIdx.x, bn = blockIdx.y;
    f32x4 acc[4][4] = {};
    const int srow = lane >> 3;
    const int scol = (lane & 7) * 8;
    const u16* Abase = A + (size_t)(bm * 128 + srow) * K + scol;
    const u16* Bbase = B + (size_t)(bn * 128 + srow) * K + scol;

    for (int k0 = 0; k0 < K; k0 += 64) {
#pragma unroll
        for (int j = 0; j < 4; ++j) {
            int chunk = wave * 4 + j;
            gl_lds16(Abase + (size_t)(chunk * 8) * K + k0, lA + chunk * 512);
            gl_lds16(Bbase + (size_t)(chunk * 8) * K + k0, lB + chunk * 512);
        }
        __syncthreads();
        const u16* pA = lA + (wr * 64 + (lane & 15)) * 64 + (lane >> 4) * 8;
        const u16* pB = lB + (wc * 64 + (lane & 15)) * 64 + (lane >> 4) * 8;
#pragma unroll
        for (int kk = 0; kk < 2; ++kk) {
            u16x8 a[4], b[4];
#pragma unroll
            for (int m = 0; m < 4; ++m) a[m] = *(const u16x8*)(pA + m * 1024 + kk * 32);
#pragma unroll
            for (int n = 0; n < 4; ++n) b[n] = *(const u16x8*)(pB + n * 1024 + kk * 32);
#pragma unroll
            for (int m = 0; m < 4; ++m)
#pragma unroll
                for (int n = 0; n < 4; ++n)
                    acc[m][n] = mfma16(a[m], b[n], acc[m][n]);
        }
        __syncthreads();
    }
    // epilogue: scatter bf16 tile to LDS (stride 136 keeps 16B alignment), then
    // coalesced row stores: 16 lanes x 16B = 256B contiguous per row.
#pragma unroll
    for (int n = 0; n < 4; ++n) {
        int cc = wc * 64 + n * 16 + (lane & 15);
        float bv = bias[bn * 128 + cc];
#pragma unroll
        for (int m = 0; m < 4; ++m) {
            int rr = wr * 64 + m * 16 + ((lane >> 4) * 4);
#pragma unroll
            for (int i = 0; i < 4; ++i) {
                float v = acc[m][n][i] + bv;
                if (EPI == 1) v = (v >= 0.0f) ? v : 0.01f * v;
                smem[(rr + i) * 136 + cc] = f2bf(v);
            }
        }
    }
    __syncthreads();
#pragma unroll
    for (int p = 0; p < 8; ++p) {
        int rr = p * 16 + wave * 4 + (lane >> 4);
        int cc = (lane & 15) * 8;
        u16x8 v = *(const u16x8*)(smem + rr * 136 + cc);
        *(u16x8*)(C + (size_t)(bm * 128 + rr) * N + bn * 128 + cc) = v;
    }
}

// ---------------------------------------------------------------------------
// Persistent LSTM chunk kernel (regular launch, static 64KB LDS).
// Grid 256 wgs x 256 thr. wg (bm,bn): batch rows [bm*64,+64), gate cols
// [bn*64,+64) = units [bn*16,+16). Whh panel in 256 VGPRs (forces 1 wave/SIMD
// -> 1 wg/CU -> all 256 wgs co-resident, so the counter barrier is safe).
// h tile staged per step in 4 double-buffered 32KB chunks, XOR-swizzled.
// ---------------------------------------------------------------------------

// Stage one [64 rows x 512B] K-chunk kc of a row-major [64][2048B] panel.
// LDS layout: row-major [64][512B], content swizzled: LDS(r,cb)=G(r,cb^((r&7)<<4)).
__device__ __forceinline__ void stage_chunk(const char* panel, char* buf, int kc,
                                            int wave, int lane) {
#pragma unroll
    for (int j = 0; j < 8; ++j) {
        int hr = wave * 8 + j;               // half-wave row pair index
        int r = hr * 2 + (lane >> 5);
        int sc = ((lane & 31) * 16) ^ ((r & 7) << 4);
        gl_lds16(panel + (size_t)r * 2048 + kc * 512 + sc, buf + (size_t)hr * 1024);
    }
}

__global__ __launch_bounds__(256, 1) void lstm_seq(
    const u16* __restrict__ xg, const u16* __restrict__ Whh,
    const int* __restrict__ dones, const float* __restrict__ Wv,
    u16* __restrict__ h0, u16* __restrict__ h1,
    float* __restrict__ cbuf, float* __restrict__ hbuf,
    float* __restrict__ value, int* __restrict__ cnt,
    int t0, int nt, int first) {
    __shared__ __align__(16) char sm[65536];   // 2 x 32KB chunk buffers; lepi reuses
    float* lepi = (float*)sm;
    const int tid = threadIdx.x;
    const int lane = tid & 63, wave = tid >> 6;
    const int wr = wave >> 1, wc = wave & 1;
    const int bm = blockIdx.x >> 6, bn = blockIdx.x & 63;

    // ---- Whh panel -> registers (once per launch), via chunked LDS staging ----
    u16x8 breg[64];
    {
        const char* wp = (const char*)(Whh + (size_t)(bn * 64) * H_DIM);
        const int rlb = wc * 32 + (lane & 15);
        const int sw = (rlb & 7) << 4;
#pragma unroll
        for (int kc = 0; kc < 4; ++kc) {
            char* buf = sm + (kc & 1) * 32768;
            stage_chunk(wp, buf, kc, wave, lane);
            __syncthreads();
#pragma unroll
            for (int s2 = 0; s2 < 8; ++s2) {
                int kb2 = s2 * 64 + (lane >> 4) * 16;
                breg[(kc * 8 + s2) * 2]     = *(const u16x8*)(buf + rlb * 512 + (kb2 ^ sw));
                breg[(kc * 8 + s2) * 2 + 1] = *(const u16x8*)(buf + (rlb + 16) * 512 + (kb2 ^ sw));
            }
            __syncthreads();
        }
    }

    // ---- per-thread epilogue state ----
    const int r = tid & 63;
    const int ublk = tid >> 6;
    const int bg = bm * 64 + r;
    const int ucol = bn * 16 + ublk * 4;
    float wv[4], c[4];
#pragma unroll
    for (int uu = 0; uu < 4; ++uu) wv[uu] = Wv[ucol + uu];
    if (first) {
        c[0] = c[1] = c[2] = c[3] = 0.0f;
    } else {
        float4 cv = *(const float4*)(cbuf + (size_t)bg * H_DIM + ucol);
        c[0] = cv.x; c[1] = cv.y; c[2] = cv.z; c[3] = cv.w;
    }

    const int rla = wr * 32 + (lane & 15);
    const int swa = (rla & 7) << 4;

    for (int tt = 0; tt < nt; ++tt) {
        const int t = t0 + tt;
        const u16* hin = (t & 1) ? h1 : h0;
        u16* hout = (t & 1) ? h0 : h1;
        const char* hp = (const char*)(hin + (size_t)(bm * 64) * H_DIM);

        // epilogue operands early (overlap with staging latency)
        const int done = dones[t * B_DIM + bg];
        u16x4 xv[4];
#pragma unroll
        for (int uu = 0; uu < 4; ++uu)
            xv[uu] = *(const u16x4*)(xg + (size_t)tt * B_DIM * G_DIM +
                                     (size_t)bg * G_DIM + bn * 64 + (ublk * 4 + uu) * 4);

        // ---- K-chunked, double-buffered h staging + MFMA ----
        stage_chunk(hp, sm, 0, wave, lane);
        __syncthreads();
        f32x4 acc[2][2] = {};
#pragma unroll
        for (int kc = 0; kc < 4; ++kc) {
            char* buf = sm + (kc & 1) * 32768;
            if (kc < 3) stage_chunk(hp, sm + ((kc + 1) & 1) * 32768, kc + 1, wave, lane);
#pragma unroll
            for (int s2 = 0; s2 < 8; ++s2) {
                int kb2 = s2 * 64 + (lane >> 4) * 16;
                u16x8 a0 = *(const u16x8*)(buf + rla * 512 + (kb2 ^ swa));
                u16x8 a1 = *(const u16x8*)(buf + (rla + 16) * 512 + (kb2 ^ swa));
                int s = kc * 8 + s2;
                acc[0][0] = mfma16(a0, breg[2 * s], acc[0][0]);
                acc[0][1] = mfma16(a0, breg[2 * s + 1], acc[0][1]);
                acc[1][0] = mfma16(a1, breg[2 * s], acc[1][0]);
                acc[1][1] = mfma16(a1, breg[2 * s + 1], acc[1][1]);
            }
            __syncthreads();   // staging kc+1 drained; reads of buf done
        }

        // ---- scatter gate pre-activations (f32) into lepi (reuses chunk LDS) ----
#pragma unroll
        for (int n = 0; n < 2; ++n)
#pragma unroll
            for (int m = 0; m < 2; ++m)
#pragma unroll
                for (int i = 0; i < 4; ++i)
                    lepi[(wr * 32 + m * 16 + (lane >> 4) * 4 + i) * 65 +
                         wc * 32 + n * 16 + (lane & 15)] = acc[m][n][i];
        __syncthreads();

        // ---- gate math: thread = (batch row r, 4 units) ----
        const float mb = (done == 0) ? 1.0f : 0.0f;
        float vpart = 0.0f;
        u16x4 hb;
        float hf[4];
#pragma unroll
        for (int uu = 0; uu < 4; ++uu) {
            const float* gp = &lepi[r * 65 + (ublk * 4 + uu) * 4];
            float gi = bf2f(xv[uu][0]) + mb * gp[0];
            float gf = bf2f(xv[uu][1]) + mb * gp[1];
            float gg = bf2f(xv[uu][2]) + mb * gp[2];
            float go = bf2f(xv[uu][3]) + mb * gp[3];
            float i_ = sigm(gi), f_ = sigm(gf), g_ = tanh_fast(gg), o_ = sigm(go);
            float cn = f_ * (mb * c[uu]) + i_ * g_;
            float hn = o_ * tanh_fast(cn);
            c[uu] = cn; hf[uu] = hn;
            hb[uu] = f2bf(hn);
            float lr = (hn >= 0.0f) ? hn : 0.01f * hn;
            vpart += lr * wv[uu];
        }
        *(u16x4*)(hout + (size_t)bg * H_DIM + ucol) = hb;
        if (t == T_DIM - 1)
            *(float4*)(hbuf + (size_t)bg * H_DIM + ucol) = make_float4(hf[0], hf[1], hf[2], hf[3]);

        // ---- value partial: wg reduce over ublk, one atomic per row ----
        __syncthreads();                    // all lepi reads done
        lepi[ublk * 64 + r] = vpart;
        __syncthreads();
        if (ublk == 0) {
            float vs = lepi[r] + lepi[64 + r] + lepi[128 + r] + lepi[192 + r];
            atomicAdd(value + t * B_DIM + bg, vs);
        }
        // ---- per-bm flag barrier (64 wgs share batch rows [bm*64,+64)) ----
        if (tid == 0) {
            __threadfence();                // L2 writeback -> device scope
            __hip_atomic_fetch_add(&cnt[bm], 1, __ATOMIC_RELEASE, __HIP_MEMORY_SCOPE_AGENT);
            while (__hip_atomic_load(&cnt[bm], __ATOMIC_ACQUIRE, __HIP_MEMORY_SCOPE_AGENT) <
                   64 * (t + 1))
                __builtin_amdgcn_s_sleep(2);
        }
        __syncthreads();
    }
    *(float4*)(cbuf + (size_t)bg * H_DIM + ucol) = make_float4(c[0], c[1], c[2], c[3]);
}

// ---------------------------------------------------------------------------
__global__ void k_cast_bf16(const float* __restrict__ in, u16* __restrict__ out, int n4) {
    int i = blockIdx.x * 256 + threadIdx.x;
    if (i < n4) {
        float4 v = *(const float4*)(in + (size_t)i * 4);
        u16x4 o;
        o[0] = f2bf(v.x); o[1] = f2bf(v.y); o[2] = f2bf(v.z); o[3] = f2bf(v.w);
        *(u16x4*)(out + (size_t)i * 4) = o;
    }
}

// out row (4n+q) = in row (q*H + n), cast to bf16.
__global__ void k_permute_w(const float* __restrict__ W, u16* __restrict__ Wp) {
    int row = blockIdx.x;
    int rin = (row & 3) * H_DIM + (row >> 2);
    int c = threadIdx.x * 4;
    float4 v = *(const float4*)(W + (size_t)rin * H_DIM + c);
    u16x4 o;
    o[0] = f2bf(v.x); o[1] = f2bf(v.y); o[2] = f2bf(v.z); o[3] = f2bf(v.w);
    *(u16x4*)(Wp + (size_t)row * H_DIM + c) = o;
}

__global__ void k_prep_bias(const float* __restrict__ b_ih, const float* __restrict__ b_hh,
                            float* __restrict__ bc) {
    int i = blockIdx.x * 256 + threadIdx.x;
    int n = i >> 2, q = i & 3;
    bc[i] = b_ih[q * H_DIM + n] + b_hh[q * H_DIM + n];
}

__global__ void k_init(float* __restrict__ value, const float* __restrict__ bv,
                       u16* __restrict__ h0, int* __restrict__ cnt) {
    int i = blockIdx.x * 256 + threadIdx.x;
    if (i < B_DIM * H_DIM) h0[i] = 0;
    if (i < T_DIM * B_DIM) value[i] = *bv;
    if (i < 4) cnt[i] = 0;
}

extern "C" void kernel_launch(void* const* d_in, const int* in_sizes, int n_in,
                              void* d_out, int out_size, void* d_ws, size_t ws_size,
                              hipStream_t stream) {
    const float* x     = (const float*)d_in[0];
    const int*   dones = (const int*)d_in[1];
    const float* W1    = (const float*)d_in[2];
    const float* b1    = (const float*)d_in[3];
    const float* W_ih  = (const float*)d_in[4];
    const float* W_hh  = (const float*)d_in[5];
    const float* b_ih  = (const float*)d_in[6];
    const float* b_hh  = (const float*)d_in[7];
    const float* Wv    = (const float*)d_in[8];
    const float* bv    = (const float*)d_in[9];

    float* out   = (float*)d_out;
    float* value = out;                          // [T*B]
    float* hbuf  = out + (size_t)T_DIM * B_DIM;  // h_T [B*H] f32
    float* cbuf  = hbuf + (size_t)B_DIM * H_DIM; // c_T [B*H] f32

    // ---- pick chunk size nt from ws_size ----
    const size_t per_nt = (size_t)(F_DIM + H_DIM + G_DIM) * B_DIM * 2;  // ~2.88MB
    const size_t fixed = (size_t)H_DIM * F_DIM * 2 + 2 * (size_t)G_DIM * H_DIM * 2 +
                         G_DIM * 4 + 2 * (size_t)B_DIM * H_DIM * 2 + 4096;
    int nt = 2;
    for (int cand = 16; cand >= 2; cand >>= 1)
        if (fixed + (size_t)cand * per_nt + 65536 <= ws_size) { nt = cand; break; }

    char* ws = (char*)d_ws;
    size_t off = 0;
    auto alloc = [&](size_t bytes) {
        void* p = ws + off;
        off = (off + bytes + 255) & ~(size_t)255;
        return p;
    };
    u16*   x_bf  = (u16*)alloc((size_t)nt * B_DIM * F_DIM * 2);
    u16*   shr   = (u16*)alloc((size_t)nt * B_DIM * H_DIM * 2);
    u16*   xg    = (u16*)alloc((size_t)nt * B_DIM * G_DIM * 2);
    u16*   W1b   = (u16*)alloc((size_t)H_DIM * F_DIM * 2);
    u16*   Wihp  = (u16*)alloc((size_t)G_DIM * H_DIM * 2);
    u16*   Whhp  = (u16*)alloc((size_t)G_DIM * H_DIM * 2);
    float* bcomb = (float*)alloc((size_t)G_DIM * 4);
    u16*   hping = (u16*)alloc((size_t)B_DIM * H_DIM * 2);
    u16*   hpong = (u16*)alloc((size_t)B_DIM * H_DIM * 2);
    int*   cnt   = (int*)alloc(256);

    // ---- weight prep ----
    k_cast_bf16<<<(H_DIM * F_DIM / 4) / 256, 256, 0, stream>>>(W1, W1b, H_DIM * F_DIM / 4);
    k_permute_w<<<G_DIM, 256, 0, stream>>>(W_ih, Wihp);
    k_permute_w<<<G_DIM, 256, 0, stream>>>(W_hh, Whhp);
    k_prep_bias<<<G_DIM / 256, 256, 0, stream>>>(b_ih, b_hh, bcomb);
    k_init<<<(B_DIM * H_DIM) / 256, 256, 0, stream>>>(value, bv, hping, cnt);

    for (int t0 = 0; t0 < T_DIM; t0 += nt) {
        int m = nt * B_DIM;
        int n4 = m * F_DIM / 4;
        k_cast_bf16<<<n4 / 256, 256, 0, stream>>>(x + (size_t)t0 * B_DIM * F_DIM, x_bf, n4);
        gemm_bt128<1><<<dim3(m / 128, H_DIM / 128), 256, 0, stream>>>(
            x_bf, W1b, b1, shr, F_DIM, H_DIM);
        gemm_bt128<0><<<dim3(m / 128, G_DIM / 128), 256, 0, stream>>>(
            shr, Wihp, bcomb, xg, H_DIM, G_DIM);

        lstm_seq<<<256, 256, 0, stream>>>(
            xg, Whhp, dones, Wv, hping, hpong, cbuf, hbuf, value, cnt,
            t0, nt, (t0 == 0) ? 1 : 0);
    }
}

// Round 5
// 4014.535 us; speedup vs baseline: 1.1801x; 1.1801x over previous
//
#include <hip/hip_runtime.h>
#include <cstdint>
#include <cstddef>

#define T_DIM 128
#define B_DIM 256
#define F_DIM 512
#define H_DIM 1024
#define G_DIM 4096   // 4*H

typedef unsigned short u16;
typedef unsigned short u16x8 __attribute__((ext_vector_type(8)));
typedef unsigned short u16x4 __attribute__((ext_vector_type(4)));
typedef __bf16 bf16x8 __attribute__((ext_vector_type(8)));
typedef float f32x4 __attribute__((ext_vector_type(4)));

__device__ __forceinline__ float bf2f(u16 u) {
    union { unsigned v; float f; } x; x.v = ((unsigned)u) << 16; return x.f;
}
__device__ __forceinline__ u16 f2bf(float f) {
    union { float f; unsigned v; } x; x.f = f;
    return (u16)((x.v + 0x7fffu + ((x.v >> 16) & 1u)) >> 16);
}

__device__ __forceinline__ f32x4 mfma16(u16x8 a, u16x8 b, f32x4 c) {
    return __builtin_amdgcn_mfma_f32_16x16x32_bf16(
        __builtin_bit_cast(bf16x8, a), __builtin_bit_cast(bf16x8, b), c, 0, 0, 0);
}

__device__ __forceinline__ void gl_lds16(const void* g, void* s) {
    __builtin_amdgcn_global_load_lds(
        (const __attribute__((address_space(1))) void*)g,
        (__attribute__((address_space(3))) void*)s, 16, 0, 0);
}

__device__ __forceinline__ float sigm(float x) { return 1.0f / (1.0f + __expf(-x)); }
__device__ __forceinline__ float tanh_fast(float x) {
    float e = __expf(2.0f * x);
    return 1.0f - 2.0f / (e + 1.0f);
}

// ---------------------------------------------------------------------------
// GEMM: C[M,N] = epi(A[M,K] * B[N,K]^T + bias), bf16 in/out, f32 accum.
// 128x128 tile, BK=64, 4 waves (2x2). Epilogue bounces C through LDS so global
// stores are 16B/lane coalesced.
// ---------------------------------------------------------------------------
template <int EPI>
__global__ __launch_bounds__(256) void gemm_bt128(
    const u16* __restrict__ A, const u16* __restrict__ B,
    const float* __restrict__ bias, u16* __restrict__ C, int K, int N) {
    __shared__ __align__(16) u16 smem[128 * 136];  // staging 16384 u16; epi 128x136
    u16* lA = smem;
    u16* lB = smem + 8192;
    const int lane = threadIdx.x & 63;
    const int wave = threadIdx.x >> 6;
    const int wr = wave >> 1, wc = wave & 1;
    const int bm = blockIdx.x, bn = blockIdx.y;
    f32x4 acc[4][4] = {};
    const int srow = lane >> 3;
    const int scol = (lane & 7) * 8;
    const u16* Abase = A + (size_t)(bm * 128 + srow) * K + scol;
    const u16* Bbase = B + (size_t)(bn * 128 + srow) * K + scol;

    for (int k0 = 0; k0 < K; k0 += 64) {
#pragma unroll
        for (int j = 0; j < 4; ++j) {
            int chunk = wave * 4 + j;
            gl_lds16(Abase + (size_t)(chunk * 8) * K + k0, lA + chunk * 512);
            gl_lds16(Bbase + (size_t)(chunk * 8) * K + k0, lB + chunk * 512);
        }
        __syncthreads();
        const u16* pA = lA + (wr * 64 + (lane & 15)) * 64 + (lane >> 4) * 8;
        const u16* pB = lB + (wc * 64 + (lane & 15)) * 64 + (lane >> 4) * 8;
#pragma unroll
        for (int kk = 0; kk < 2; ++kk) {
            u16x8 a[4], b[4];
#pragma unroll
            for (int m = 0; m < 4; ++m) a[m] = *(const u16x8*)(pA + m * 1024 + kk * 32);
#pragma unroll
            for (int n = 0; n < 4; ++n) b[n] = *(const u16x8*)(pB + n * 1024 + kk * 32);
#pragma unroll
            for (int m = 0; m < 4; ++m)
#pragma unroll
                for (int n = 0; n < 4; ++n)
                    acc[m][n] = mfma16(a[m], b[n], acc[m][n]);
        }
        __syncthreads();
    }
#pragma unroll
    for (int n = 0; n < 4; ++n) {
        int cc = wc * 64 + n * 16 + (lane & 15);
        float bv = bias[bn * 128 + cc];
#pragma unroll
        for (int m = 0; m < 4; ++m) {
            int rr = wr * 64 + m * 16 + ((lane >> 4) * 4);
#pragma unroll
            for (int i = 0; i < 4; ++i) {
                float v = acc[m][n][i] + bv;
                if (EPI == 1) v = (v >= 0.0f) ? v : 0.01f * v;
                smem[(rr + i) * 136 + cc] = f2bf(v);
            }
        }
    }
    __syncthreads();
#pragma unroll
    for (int p = 0; p < 8; ++p) {
        int rr = p * 16 + wave * 4 + (lane >> 4);
        int cc = (lane & 15) * 8;
        u16x8 v = *(const u16x8*)(smem + rr * 136 + cc);
        *(u16x8*)(C + (size_t)(bm * 128 + rr) * N + bn * 128 + cc) = v;
    }
}

// ---------------------------------------------------------------------------
// Persistent LSTM chunk kernel. Grid 256 wgs x 256 thr, 1 wg/CU.
// wg (bm,bn): batch rows [bm*64,+64), gate cols [bn*64,+64).
// Wave w owns gate cols [bn*64 + w*16, +16): breg = 32 frags = 128 VGPRs
// (R4's 256-VGPR breg spilled to scratch at VGPR_Count=196 -> 33us/step).
// h tile staged per step in 4 double-buffered 32KB chunks, XOR-swizzled.
// value via per-wg partial slots + owner-summed next step (no atomics).
// ---------------------------------------------------------------------------

// Stage one [64 rows x 512B] K-chunk kc of a row-major [64][2048B] panel.
// LDS: row-major [64][512B], content swizzled: LDS(r,cb)=G(r,cb^((r&7)<<4)).
__device__ __forceinline__ void stage_chunk(const char* panel, char* buf, int kc,
                                            int wave, int lane) {
#pragma unroll
    for (int j = 0; j < 8; ++j) {
        int hr = wave * 8 + j;               // half-row pair index
        int r = hr * 2 + (lane >> 5);
        int sc = ((lane & 31) * 16) ^ ((r & 7) << 4);
        gl_lds16(panel + (size_t)r * 2048 + kc * 512 + sc, buf + (size_t)hr * 1024);
    }
}

__global__ __launch_bounds__(256, 1) void lstm_seq(
    const u16* __restrict__ xg, const u16* __restrict__ Whh,
    const int* __restrict__ dones, const float* __restrict__ Wv,
    u16* __restrict__ h0, u16* __restrict__ h1,
    float* __restrict__ cbuf, float* __restrict__ hbuf,
    float* __restrict__ value, int* __restrict__ cnt,
    float* __restrict__ vpartial, int t0, int nt, int first) {
    __shared__ __align__(16) char sm[65536];   // 2 x 32KB chunk buffers; lepi reuses
    float* lepi = (float*)sm;
    const int tid = threadIdx.x;
    const int lane = tid & 63, wave = tid >> 6;
    const int bm = blockIdx.x >> 6, bn = blockIdx.x & 63;
    const int sw = (lane & 7) << 4;            // row-XOR swizzle (rows stride 16 -> &7 = lane&7)

    // ---- Whh panel: wave w holds gate cols [w*16,+16), all K -> 128 VGPRs ----
    u16x8 breg[32];
    {
        const char* wp = (const char*)(Whh + (size_t)(bn * 64) * H_DIM);
        const int rlb = wave * 16 + (lane & 15);
#pragma unroll
        for (int kc = 0; kc < 4; ++kc) {
            char* buf = sm + (kc & 1) * 32768;
            stage_chunk(wp, buf, kc, wave, lane);
            __syncthreads();
#pragma unroll
            for (int s2 = 0; s2 < 8; ++s2) {
                int kb2 = s2 * 64 + (lane >> 4) * 16;
                breg[kc * 8 + s2] = *(const u16x8*)(buf + rlb * 512 + (kb2 ^ sw));
            }
            __syncthreads();
        }
    }

    // ---- per-thread epilogue state ----
    const int r = tid & 63;
    const int ublk = tid >> 6;
    const int bg = bm * 64 + r;
    const int ucol = bn * 16 + ublk * 4;
    float wv[4], c[4];
#pragma unroll
    for (int uu = 0; uu < 4; ++uu) wv[uu] = Wv[ucol + uu];
    if (first) {
        c[0] = c[1] = c[2] = c[3] = 0.0f;
    } else {
        float4 cv = *(const float4*)(cbuf + (size_t)bg * H_DIM + ucol);
        c[0] = cv.x; c[1] = cv.y; c[2] = cv.z; c[3] = cv.w;
    }

    for (int tt = 0; tt < nt; ++tt) {
        const int t = t0 + tt;
        const u16* hin = (t & 1) ? h1 : h0;
        u16* hout = (t & 1) ? h0 : h1;
        const char* hp = (const char*)(hin + (size_t)(bm * 64) * H_DIM);
        const int done = dones[t * B_DIM + bg];

        // ---- kick off first h chunk; wave 0 sums value(t-1) under its latency ----
        stage_chunk(hp, sm, 0, wave, lane);
        if (t > 0 && tid < 64) {
            float4 v4 = *(const float4*)(vpartial + (size_t)((t - 1) & 1) * 65536 +
                                         (size_t)(bm * 64 + bn) * 256 + lane * 4);
            float s = v4.x + v4.y + v4.z + v4.w;
#pragma unroll
            for (int m2 = 32; m2 >= 1; m2 >>= 1) s += __shfl_xor(s, m2);
            if (tid == 0) value[(t - 1) * B_DIM + bm * 64 + bn] += s;
        }
        __syncthreads();

        // ---- K-chunked, double-buffered MFMA: acc[m] = rows m*16.., cols wave*16.. ----
        f32x4 acc[4] = {};
#pragma unroll
        for (int kc = 0; kc < 4; ++kc) {
            char* buf = sm + (kc & 1) * 32768;
            if (kc < 3) stage_chunk(hp, sm + ((kc + 1) & 1) * 32768, kc + 1, wave, lane);
#pragma unroll
            for (int s2 = 0; s2 < 8; ++s2) {
                int kb2 = s2 * 64 + (lane >> 4) * 16;
#pragma unroll
                for (int m = 0; m < 4; ++m) {
                    u16x8 a = *(const u16x8*)(buf + (m * 16 + (lane & 15)) * 512 + (kb2 ^ sw));
                    acc[m] = mfma16(a, breg[kc * 8 + s2], acc[m]);
                }
            }
            __syncthreads();   // staging kc+1 drained; reads of buf done
        }

        // xg operands (needed post-scatter; load now, latency hides under scatter+sync)
        u16x4 xv[4];
#pragma unroll
        for (int uu = 0; uu < 4; ++uu)
            xv[uu] = *(const u16x4*)(xg + (size_t)tt * B_DIM * G_DIM +
                                     (size_t)bg * G_DIM + bn * 64 + (ublk * 4 + uu) * 4);

        // ---- scatter gate pre-activations (f32) into lepi (reuses chunk LDS) ----
#pragma unroll
        for (int m = 0; m < 4; ++m)
#pragma unroll
            for (int i = 0; i < 4; ++i)
                lepi[(m * 16 + (lane >> 4) * 4 + i) * 65 + wave * 16 + (lane & 15)] = acc[m][i];
        __syncthreads();

        // ---- gate math: thread = (batch row r, 4 units) ----
        const float mb = (done == 0) ? 1.0f : 0.0f;
        float vpart = 0.0f;
        u16x4 hb;
        float hf[4];
#pragma unroll
        for (int uu = 0; uu < 4; ++uu) {
            const float* gp = &lepi[r * 65 + (ublk * 4 + uu) * 4];
            float gi = bf2f(xv[uu][0]) + mb * gp[0];
            float gf = bf2f(xv[uu][1]) + mb * gp[1];
            float gg = bf2f(xv[uu][2]) + mb * gp[2];
            float go = bf2f(xv[uu][3]) + mb * gp[3];
            float i_ = sigm(gi), f_ = sigm(gf), g_ = tanh_fast(gg), o_ = sigm(go);
            float cn = f_ * (mb * c[uu]) + i_ * g_;
            float hn = o_ * tanh_fast(cn);
            c[uu] = cn; hf[uu] = hn;
            hb[uu] = f2bf(hn);
            float lr = (hn >= 0.0f) ? hn : 0.01f * hn;
            vpart += lr * wv[uu];
        }
        *(u16x4*)(hout + (size_t)bg * H_DIM + ucol) = hb;
        if (t == T_DIM - 1)
            *(float4*)(hbuf + (size_t)bg * H_DIM + ucol) = make_float4(hf[0], hf[1], hf[2], hf[3]);
        // value partial slot (summed by owner wg at step t+1; no atomics)
        vpartial[(size_t)(t & 1) * 65536 + (size_t)bg * 256 + bn * 4 + ublk] = vpart;

        // ---- per-bm flag barrier (cnt padded to 256B/bm) ----
        if (tid == 0) {
            __threadfence();
            __hip_atomic_fetch_add(&cnt[bm * 64], 1, __ATOMIC_RELEASE, __HIP_MEMORY_SCOPE_AGENT);
            while (__hip_atomic_load(&cnt[bm * 64], __ATOMIC_ACQUIRE, __HIP_MEMORY_SCOPE_AGENT) <
                   64 * (t + 1))
                __builtin_amdgcn_s_sleep(2);
        }
        __syncthreads();
    }
    *(float4*)(cbuf + (size_t)bg * H_DIM + ucol) = make_float4(c[0], c[1], c[2], c[3]);

    // ---- final value row (t = T-1): all wgs passed the last barrier above ----
    if (t0 + nt == T_DIM && tid < 64) {
        float4 v4 = *(const float4*)(vpartial + (size_t)((T_DIM - 1) & 1) * 65536 +
                                     (size_t)(bm * 64 + bn) * 256 + lane * 4);
        float s = v4.x + v4.y + v4.z + v4.w;
#pragma unroll
        for (int m2 = 32; m2 >= 1; m2 >>= 1) s += __shfl_xor(s, m2);
        if (tid == 0) value[(T_DIM - 1) * B_DIM + bm * 64 + bn] += s;
    }
}

// ---------------------------------------------------------------------------
__global__ void k_cast_bf16(const float* __restrict__ in, u16* __restrict__ out, int n4) {
    int i = blockIdx.x * 256 + threadIdx.x;
    if (i < n4) {
        float4 v = *(const float4*)(in + (size_t)i * 4);
        u16x4 o;
        o[0] = f2bf(v.x); o[1] = f2bf(v.y); o[2] = f2bf(v.z); o[3] = f2bf(v.w);
        *(u16x4*)(out + (size_t)i * 4) = o;
    }
}

// out row (4n+q) = in row (q*H + n), cast to bf16.
__global__ void k_permute_w(const float* __restrict__ W, u16* __restrict__ Wp) {
    int row = blockIdx.x;
    int rin = (row & 3) * H_DIM + (row >> 2);
    int c = threadIdx.x * 4;
    float4 v = *(const float4*)(W + (size_t)rin * H_DIM + c);
    u16x4 o;
    o[0] = f2bf(v.x); o[1] = f2bf(v.y); o[2] = f2bf(v.z); o[3] = f2bf(v.w);
    *(u16x4*)(Wp + (size_t)row * H_DIM + c) = o;
}

__global__ void k_prep_bias(const float* __restrict__ b_ih, const float* __restrict__ b_hh,
                            float* __restrict__ bc) {
    int i = blockIdx.x * 256 + threadIdx.x;
    int n = i >> 2, q = i & 3;
    bc[i] = b_ih[q * H_DIM + n] + b_hh[q * H_DIM + n];
}

__global__ void k_init(float* __restrict__ value, const float* __restrict__ bv,
                       u16* __restrict__ h0, int* __restrict__ cnt) {
    int i = blockIdx.x * 256 + threadIdx.x;
    if (i < B_DIM * H_DIM) h0[i] = 0;
    if (i < T_DIM * B_DIM) value[i] = *bv;
    if (i < 256) cnt[i] = 0;
}

extern "C" void kernel_launch(void* const* d_in, const int* in_sizes, int n_in,
                              void* d_out, int out_size, void* d_ws, size_t ws_size,
                              hipStream_t stream) {
    const float* x     = (const float*)d_in[0];
    const int*   dones = (const int*)d_in[1];
    const float* W1    = (const float*)d_in[2];
    const float* b1    = (const float*)d_in[3];
    const float* W_ih  = (const float*)d_in[4];
    const float* W_hh  = (const float*)d_in[5];
    const float* b_ih  = (const float*)d_in[6];
    const float* b_hh  = (const float*)d_in[7];
    const float* Wv    = (const float*)d_in[8];
    const float* bv    = (const float*)d_in[9];

    float* out   = (float*)d_out;
    float* value = out;                          // [T*B]
    float* hbuf  = out + (size_t)T_DIM * B_DIM;  // h_T [B*H] f32
    float* cbuf  = hbuf + (size_t)B_DIM * H_DIM; // c_T [B*H] f32

    // ---- pick chunk size nt from ws_size ----
    const size_t per_nt = (size_t)(F_DIM + H_DIM + G_DIM) * B_DIM * 2;  // ~2.88MB
    const size_t fixed = (size_t)H_DIM * F_DIM * 2 + 2 * (size_t)G_DIM * H_DIM * 2 +
                         G_DIM * 4 + 2 * (size_t)B_DIM * H_DIM * 2 +
                         2 * 65536 * 4 + 8192;
    int nt = 2;
    for (int cand = 16; cand >= 2; cand >>= 1)
        if (fixed + (size_t)cand * per_nt + 65536 <= ws_size) { nt = cand; break; }

    char* ws = (char*)d_ws;
    size_t off = 0;
    auto alloc = [&](size_t bytes) {
        void* p = ws + off;
        off = (off + bytes + 255) & ~(size_t)255;
        return p;
    };
    u16*   x_bf   = (u16*)alloc((size_t)nt * B_DIM * F_DIM * 2);
    u16*   shr    = (u16*)alloc((size_t)nt * B_DIM * H_DIM * 2);
    u16*   xg     = (u16*)alloc((size_t)nt * B_DIM * G_DIM * 2);
    u16*   W1b    = (u16*)alloc((size_t)H_DIM * F_DIM * 2);
    u16*   Wihp   = (u16*)alloc((size_t)G_DIM * H_DIM * 2);
    u16*   Whhp   = (u16*)alloc((size_t)G_DIM * H_DIM * 2);
    float* bcomb  = (float*)alloc((size_t)G_DIM * 4);
    u16*   hping  = (u16*)alloc((size_t)B_DIM * H_DIM * 2);
    u16*   hpong  = (u16*)alloc((size_t)B_DIM * H_DIM * 2);
    int*   cnt    = (int*)alloc(256 * 4);
    float* vpart  = (float*)alloc(2 * 65536 * 4);

    // ---- weight prep ----
    k_cast_bf16<<<(H_DIM * F_DIM / 4) / 256, 256, 0, stream>>>(W1, W1b, H_DIM * F_DIM / 4);
    k_permute_w<<<G_DIM, 256, 0, stream>>>(W_ih, Wihp);
    k_permute_w<<<G_DIM, 256, 0, stream>>>(W_hh, Whhp);
    k_prep_bias<<<G_DIM / 256, 256, 0, stream>>>(b_ih, b_hh, bcomb);
    k_init<<<(B_DIM * H_DIM) / 256, 256, 0, stream>>>(value, bv, hping, cnt);

    for (int t0 = 0; t0 < T_DIM; t0 += nt) {
        int m = nt * B_DIM;
        int n4 = m * F_DIM / 4;
        k_cast_bf16<<<n4 / 256, 256, 0, stream>>>(x + (size_t)t0 * B_DIM * F_DIM, x_bf, n4);
        gemm_bt128<1><<<dim3(m / 128, H_DIM / 128), 256, 0, stream>>>(
            x_bf, W1b, b1, shr, F_DIM, H_DIM);
        gemm_bt128<0><<<dim3(m / 128, G_DIM / 128), 256, 0, stream>>>(
            shr, Wihp, bcomb, xg, H_DIM, G_DIM);

        lstm_seq<<<256, 256, 0, stream>>>(
            xg, Whhp, dones, Wv, hping, hpong, cbuf, hbuf, value, cnt, vpart,
            t0, nt, (t0 == 0) ? 1 : 0);
    }
}

// Round 7
// 3211.375 us; speedup vs baseline: 1.4753x; 1.2501x over previous
//
#include <hip/hip_runtime.h>
#include <cstdint>
#include <cstddef>

#define T_DIM 128
#define B_DIM 256
#define F_DIM 512
#define H_DIM 1024
#define G_DIM 4096   // 4*H

typedef unsigned short u16;
typedef unsigned short u16x8 __attribute__((ext_vector_type(8)));
typedef unsigned short u16x4 __attribute__((ext_vector_type(4)));
typedef __bf16 bf16x8 __attribute__((ext_vector_type(8)));
typedef float f32x4 __attribute__((ext_vector_type(4)));

__device__ __forceinline__ float bf2f(u16 u) {
    union { unsigned v; float f; } x; x.v = ((unsigned)u) << 16; return x.f;
}
__device__ __forceinline__ u16 f2bf(float f) {
    union { float f; unsigned v; } x; x.f = f;
    return (u16)((x.v + 0x7fffu + ((x.v >> 16) & 1u)) >> 16);
}

__device__ __forceinline__ f32x4 mfma16(u16x8 a, u16x8 b, f32x4 c) {
    return __builtin_amdgcn_mfma_f32_16x16x32_bf16(
        __builtin_bit_cast(bf16x8, a), __builtin_bit_cast(bf16x8, b), c, 0, 0, 0);
}

__device__ __forceinline__ void gl_lds16(const void* g, void* s) {
    __builtin_amdgcn_global_load_lds(
        (const __attribute__((address_space(1))) void*)g,
        (__attribute__((address_space(3))) void*)s, 16, 0, 0);
}

__device__ __forceinline__ float sigm(float x) { return 1.0f / (1.0f + __expf(-x)); }
__device__ __forceinline__ float tanh_fast(float x) {
    float e = __expf(2.0f * x);
    return 1.0f - 2.0f / (e + 1.0f);
}

// ---------------------------------------------------------------------------
// GEMM: C[M,N] = epi(A[M,K] * B[N,K]^T + bias), bf16 in/out, f32 accum.
// 128x128 tile, BK=64, 4 waves (2x2). LDS-bounce epilogue for coalesced C.
// ---------------------------------------------------------------------------
template <int EPI>
__global__ __launch_bounds__(256) void gemm_bt128(
    const u16* __restrict__ A, const u16* __restrict__ B,
    const float* __restrict__ bias, u16* __restrict__ C, int K, int N) {
    __shared__ __align__(16) u16 smem[128 * 136];
    u16* lA = smem;
    u16* lB = smem + 8192;
    const int lane = threadIdx.x & 63;
    const int wave = threadIdx.x >> 6;
    const int wr = wave >> 1, wc = wave & 1;
    const int bm = blockIdx.x, bn = blockIdx.y;
    f32x4 acc[4][4] = {};
    const int srow = lane >> 3;
    const int scol = (lane & 7) * 8;
    const u16* Abase = A + (size_t)(bm * 128 + srow) * K + scol;
    const u16* Bbase = B + (size_t)(bn * 128 + srow) * K + scol;

    for (int k0 = 0; k0 < K; k0 += 64) {
#pragma unroll
        for (int j = 0; j < 4; ++j) {
            int chunk = wave * 4 + j;
            gl_lds16(Abase + (size_t)(chunk * 8) * K + k0, lA + chunk * 512);
            gl_lds16(Bbase + (size_t)(chunk * 8) * K + k0, lB + chunk * 512);
        }
        __syncthreads();
        const u16* pA = lA + (wr * 64 + (lane & 15)) * 64 + (lane >> 4) * 8;
        const u16* pB = lB + (wc * 64 + (lane & 15)) * 64 + (lane >> 4) * 8;
#pragma unroll
        for (int kk = 0; kk < 2; ++kk) {
            u16x8 a[4], b[4];
#pragma unroll
            for (int m = 0; m < 4; ++m) a[m] = *(const u16x8*)(pA + m * 1024 + kk * 32);
#pragma unroll
            for (int n = 0; n < 4; ++n) b[n] = *(const u16x8*)(pB + n * 1024 + kk * 32);
#pragma unroll
            for (int m = 0; m < 4; ++m)
#pragma unroll
                for (int n = 0; n < 4; ++n)
                    acc[m][n] = mfma16(a[m], b[n], acc[m][n]);
        }
        __syncthreads();
    }
#pragma unroll
    for (int n = 0; n < 4; ++n) {
        int cc = wc * 64 + n * 16 + (lane & 15);
        float bv = bias[bn * 128 + cc];
#pragma unroll
        for (int m = 0; m < 4; ++m) {
            int rr = wr * 64 + m * 16 + ((lane >> 4) * 4);
#pragma unroll
            for (int i = 0; i < 4; ++i) {
                float v = acc[m][n][i] + bv;
                if (EPI == 1) v = (v >= 0.0f) ? v : 0.01f * v;
                smem[(rr + i) * 136 + cc] = f2bf(v);
            }
        }
    }
    __syncthreads();
#pragma unroll
    for (int p = 0; p < 8; ++p) {
        int rr = p * 16 + wave * 4 + (lane >> 4);
        int cc = (lane & 15) * 8;
        u16x8 v = *(const u16x8*)(smem + rr * 136 + cc);
        *(u16x8*)(C + (size_t)(bm * 128 + rr) * N + bn * 128 + cc) = v;
    }
}

// ---------------------------------------------------------------------------
// Persistent LSTM chunk kernel. Grid 256 wgs x 256 thr.
// wg (bm = bid&3, bn = bid>>2): batch rows [bm*64,+64), gate cols [bn*64,+64).
// Wave w owns gate cols [bn*64 + w*16, +16): breg = 32 frags = 128 VGPRs.
// Sync: per-wg release-store flag + wave0 acquire-poll of all 64 group flags.
// R6 bug fixed here: the final value reduce (t=T-1) must ALSO poll for all
// group flags == T before reading other wgs' vpartial slots.
// ---------------------------------------------------------------------------

// Stage one [64 rows x 512B] K-chunk kc of a row-major [64][2048B] panel.
// LDS: row-major [64][512B], content swizzled: LDS(r,cb)=G(r,cb^((r&7)<<4)).
__device__ __forceinline__ void stage_chunk(const char* panel, char* buf, int kc,
                                            int wave, int lane) {
#pragma unroll
    for (int j = 0; j < 8; ++j) {
        int hr = wave * 8 + j;               // half-row pair index
        int r = hr * 2 + (lane >> 5);
        int sc = ((lane & 31) * 16) ^ ((r & 7) << 4);
        gl_lds16(panel + (size_t)r * 2048 + kc * 512 + sc, buf + (size_t)hr * 1024);
    }
}

__global__ __launch_bounds__(256, 1) void lstm_seq(
    const u16* __restrict__ xg, const u16* __restrict__ Whh,
    const int* __restrict__ dones, const float* __restrict__ Wv,
    u16* __restrict__ h0, u16* __restrict__ h1,
    float* __restrict__ cbuf, float* __restrict__ hbuf,
    float* __restrict__ value, int* __restrict__ flags,
    float* __restrict__ vpartial, int t0, int nt, int first) {
    __shared__ __align__(16) char sm[65536];   // 2 x 32KB chunk buffers; lepi reuses
    float* lepi = (float*)sm;
    const int tid = threadIdx.x;
    const int lane = tid & 63, wave = tid >> 6;
    const int bm = blockIdx.x & 3, bn = blockIdx.x >> 2;   // XCD-pair locality per bm
    const int sw = (lane & 7) << 4;

    // ---- Whh panel: wave w holds gate cols [w*16,+16), all K -> 128 VGPRs ----
    u16x8 breg[32];
    {
        const char* wp = (const char*)(Whh + (size_t)(bn * 64) * H_DIM);
        const int rlb = wave * 16 + (lane & 15);
#pragma unroll
        for (int kc = 0; kc < 4; ++kc) {
            char* buf = sm + (kc & 1) * 32768;
            stage_chunk(wp, buf, kc, wave, lane);
            __syncthreads();
#pragma unroll
            for (int s2 = 0; s2 < 8; ++s2) {
                int kb2 = s2 * 64 + (lane >> 4) * 16;
                breg[kc * 8 + s2] = *(const u16x8*)(buf + rlb * 512 + (kb2 ^ sw));
            }
            __syncthreads();
        }
    }

    // ---- per-thread epilogue state ----
    const int r = tid & 63;
    const int ublk = tid >> 6;
    const int bg = bm * 64 + r;
    const int ucol = bn * 16 + ublk * 4;
    float wv[4], c[4];
#pragma unroll
    for (int uu = 0; uu < 4; ++uu) wv[uu] = Wv[ucol + uu];
    if (first) {
        c[0] = c[1] = c[2] = c[3] = 0.0f;
    } else {
        float4 cv = *(const float4*)(cbuf + (size_t)bg * H_DIM + ucol);
        c[0] = cv.x; c[1] = cv.y; c[2] = cv.z; c[3] = cv.w;
    }

    for (int tt = 0; tt < nt; ++tt) {
        const int t = t0 + tt;
        const u16* hin = (t & 1) ? h1 : h0;
        u16* hout = (t & 1) ? h0 : h1;
        const char* hp = (const char*)(hin + (size_t)(bm * 64) * H_DIM);

        // step-constant data: load BEFORE the poll (independent of flags)
        const int done = dones[t * B_DIM + bg];
        u16x4 xv[4];
#pragma unroll
        for (int uu = 0; uu < 4; ++uu)
            xv[uu] = *(const u16x4*)(xg + (size_t)tt * B_DIM * G_DIM +
                                     (size_t)bg * G_DIM + bn * 64 + (ublk * 4 + uu) * 4);

        // ---- acquire-poll: wave 0, one flag per lane, no RMW ----
        if (t > 0 && tid < 64) {
            while (__hip_atomic_load(&flags[bm * 64 + tid], __ATOMIC_ACQUIRE,
                                     __HIP_MEMORY_SCOPE_AGENT) < t)
                __builtin_amdgcn_s_sleep(1);
        }
        __syncthreads();

        // ---- stage chunk 0; value(t-1) reduce overlaps its latency ----
        stage_chunk(hp, sm, 0, wave, lane);
        if (t > 0 && tid < 64) {
            float4 v4 = *(const float4*)(vpartial + (size_t)((t - 1) & 1) * 65536 +
                                         (size_t)(bm * 64 + bn) * 256 + lane * 4);
            float s = v4.x + v4.y + v4.z + v4.w;
#pragma unroll
            for (int m2 = 32; m2 >= 1; m2 >>= 1) s += __shfl_xor(s, m2);
            if (tid == 0) value[(t - 1) * B_DIM + bm * 64 + bn] += s;
        }
        __syncthreads();

        // ---- K-chunked, double-buffered MFMA: acc[m] = rows m*16.., cols wave*16 ----
        f32x4 acc[4] = {};
#pragma unroll
        for (int kc = 0; kc < 4; ++kc) {
            char* buf = sm + (kc & 1) * 32768;
            if (kc < 3) stage_chunk(hp, sm + ((kc + 1) & 1) * 32768, kc + 1, wave, lane);
#pragma unroll
            for (int s2 = 0; s2 < 8; ++s2) {
                int kb2 = s2 * 64 + (lane >> 4) * 16;
#pragma unroll
                for (int m = 0; m < 4; ++m) {
                    u16x8 a = *(const u16x8*)(buf + (m * 16 + (lane & 15)) * 512 + (kb2 ^ sw));
                    acc[m] = mfma16(a, breg[kc * 8 + s2], acc[m]);
                }
            }
            __syncthreads();
        }

        // ---- scatter gate pre-activations (f32) into lepi ----
#pragma unroll
        for (int m = 0; m < 4; ++m)
#pragma unroll
            for (int i = 0; i < 4; ++i)
                lepi[(m * 16 + (lane >> 4) * 4 + i) * 65 + wave * 16 + (lane & 15)] = acc[m][i];
        __syncthreads();

        // ---- gate math: thread = (batch row r, 4 units) ----
        const float mb = (done == 0) ? 1.0f : 0.0f;
        float vpart = 0.0f;
        u16x4 hb;
        float hf[4];
#pragma unroll
        for (int uu = 0; uu < 4; ++uu) {
            const float* gp = &lepi[r * 65 + (ublk * 4 + uu) * 4];
            float gi = bf2f(xv[uu][0]) + mb * gp[0];
            float gf = bf2f(xv[uu][1]) + mb * gp[1];
            float gg = bf2f(xv[uu][2]) + mb * gp[2];
            float go = bf2f(xv[uu][3]) + mb * gp[3];
            float i_ = sigm(gi), f_ = sigm(gf), g_ = tanh_fast(gg), o_ = sigm(go);
            float cn = f_ * (mb * c[uu]) + i_ * g_;
            float hn = o_ * tanh_fast(cn);
            c[uu] = cn; hf[uu] = hn;
            hb[uu] = f2bf(hn);
            float lr = (hn >= 0.0f) ? hn : 0.01f * hn;
            vpart += lr * wv[uu];
        }
        *(u16x4*)(hout + (size_t)bg * H_DIM + ucol) = hb;
        if (t == T_DIM - 1)
            *(float4*)(hbuf + (size_t)bg * H_DIM + ucol) = make_float4(hf[0], hf[1], hf[2], hf[3]);
        vpartial[(size_t)(t & 1) * 65536 + (size_t)bg * 256 + bn * 4 + ublk] = vpart;

        // ---- release: syncthreads drains all waves' stores to L2, then one
        //      release-store (wbl2) publishes them + the flag. No RMW, no inv. ----
        __syncthreads();
        if (tid == 0)
            __hip_atomic_store(&flags[bm * 64 + bn], t + 1, __ATOMIC_RELEASE,
                               __HIP_MEMORY_SCOPE_AGENT);
    }
    *(float4*)(cbuf + (size_t)bg * H_DIM + ucol) = make_float4(c[0], c[1], c[2], c[3]);

    // ---- final value row (t = T-1): MUST wait for all group wgs to publish
    //      their step-(T-1) vpartial before reading (the R6 race). ----
    if (t0 + nt == T_DIM && tid < 64) {
        while (__hip_atomic_load(&flags[bm * 64 + tid], __ATOMIC_ACQUIRE,
                                 __HIP_MEMORY_SCOPE_AGENT) < T_DIM)
            __builtin_amdgcn_s_sleep(1);
        float4 v4 = *(const float4*)(vpartial + (size_t)((T_DIM - 1) & 1) * 65536 +
                                     (size_t)(bm * 64 + bn) * 256 + lane * 4);
        float s = v4.x + v4.y + v4.z + v4.w;
#pragma unroll
        for (int m2 = 32; m2 >= 1; m2 >>= 1) s += __shfl_xor(s, m2);
        if (tid == 0) value[(T_DIM - 1) * B_DIM + bm * 64 + bn] += s;
    }
}

// ---------------------------------------------------------------------------
__global__ void k_cast_bf16(const float* __restrict__ in, u16* __restrict__ out, int n4) {
    int i = blockIdx.x * 256 + threadIdx.x;
    if (i < n4) {
        float4 v = *(const float4*)(in + (size_t)i * 4);
        u16x4 o;
        o[0] = f2bf(v.x); o[1] = f2bf(v.y); o[2] = f2bf(v.z); o[3] = f2bf(v.w);
        *(u16x4*)(out + (size_t)i * 4) = o;
    }
}

__global__ void k_permute_w(const float* __restrict__ W, u16* __restrict__ Wp) {
    int row = blockIdx.x;
    int rin = (row & 3) * H_DIM + (row >> 2);
    int c = threadIdx.x * 4;
    float4 v = *(const float4*)(W + (size_t)rin * H_DIM + c);
    u16x4 o;
    o[0] = f2bf(v.x); o[1] = f2bf(v.y); o[2] = f2bf(v.z); o[3] = f2bf(v.w);
    *(u16x4*)(Wp + (size_t)row * H_DIM + c) = o;
}

__global__ void k_prep_bias(const float* __restrict__ b_ih, const float* __restrict__ b_hh,
                            float* __restrict__ bc) {
    int i = blockIdx.x * 256 + threadIdx.x;
    int n = i >> 2, q = i & 3;
    bc[i] = b_ih[q * H_DIM + n] + b_hh[q * H_DIM + n];
}

__global__ void k_init(float* __restrict__ value, const float* __restrict__ bv,
                       u16* __restrict__ h0, int* __restrict__ flags) {
    int i = blockIdx.x * 256 + threadIdx.x;
    if (i < B_DIM * H_DIM) h0[i] = 0;
    if (i < T_DIM * B_DIM) value[i] = *bv;
    if (i < 256) flags[i] = 0;
}

extern "C" void kernel_launch(void* const* d_in, const int* in_sizes, int n_in,
                              void* d_out, int out_size, void* d_ws, size_t ws_size,
                              hipStream_t stream) {
    const float* x     = (const float*)d_in[0];
    const int*   dones = (const int*)d_in[1];
    const float* W1    = (const float*)d_in[2];
    const float* b1    = (const float*)d_in[3];
    const float* W_ih  = (const float*)d_in[4];
    const float* W_hh  = (const float*)d_in[5];
    const float* b_ih  = (const float*)d_in[6];
    const float* b_hh  = (const float*)d_in[7];
    const float* Wv    = (const float*)d_in[8];
    const float* bv    = (const float*)d_in[9];

    float* out   = (float*)d_out;
    float* value = out;                          // [T*B]
    float* hbuf  = out + (size_t)T_DIM * B_DIM;  // h_T [B*H] f32
    float* cbuf  = hbuf + (size_t)B_DIM * H_DIM; // c_T [B*H] f32

    const size_t per_nt = (size_t)(F_DIM + H_DIM + G_DIM) * B_DIM * 2;
    const size_t fixed = (size_t)H_DIM * F_DIM * 2 + 2 * (size_t)G_DIM * H_DIM * 2 +
                         G_DIM * 4 + 2 * (size_t)B_DIM * H_DIM * 2 +
                         2 * 65536 * 4 + 8192;
    int nt = 2;
    for (int cand = 16; cand >= 2; cand >>= 1)
        if (fixed + (size_t)cand * per_nt + 65536 <= ws_size) { nt = cand; break; }

    char* ws = (char*)d_ws;
    size_t off = 0;
    auto alloc = [&](size_t bytes) {
        void* p = ws + off;
        off = (off + bytes + 255) & ~(size_t)255;
        return p;
    };
    u16*   x_bf   = (u16*)alloc((size_t)nt * B_DIM * F_DIM * 2);
    u16*   shr    = (u16*)alloc((size_t)nt * B_DIM * H_DIM * 2);
    u16*   xg     = (u16*)alloc((size_t)nt * B_DIM * G_DIM * 2);
    u16*   W1b    = (u16*)alloc((size_t)H_DIM * F_DIM * 2);
    u16*   Wihp   = (u16*)alloc((size_t)G_DIM * H_DIM * 2);
    u16*   Whhp   = (u16*)alloc((size_t)G_DIM * H_DIM * 2);
    float* bcomb  = (float*)alloc((size_t)G_DIM * 4);
    u16*   hping  = (u16*)alloc((size_t)B_DIM * H_DIM * 2);
    u16*   hpong  = (u16*)alloc((size_t)B_DIM * H_DIM * 2);
    int*   flags  = (int*)alloc(256 * 4);
    float* vpart  = (float*)alloc(2 * 65536 * 4);

    // ---- weight prep ----
    k_cast_bf16<<<(H_DIM * F_DIM / 4) / 256, 256, 0, stream>>>(W1, W1b, H_DIM * F_DIM / 4);
    k_permute_w<<<G_DIM, 256, 0, stream>>>(W_ih, Wihp);
    k_permute_w<<<G_DIM, 256, 0, stream>>>(W_hh, Whhp);
    k_prep_bias<<<G_DIM / 256, 256, 0, stream>>>(b_ih, b_hh, bcomb);
    k_init<<<(B_DIM * H_DIM) / 256, 256, 0, stream>>>(value, bv, hping, flags);

    for (int t0 = 0; t0 < T_DIM; t0 += nt) {
        int m = nt * B_DIM;
        int n4 = m * F_DIM / 4;
        k_cast_bf16<<<n4 / 256, 256, 0, stream>>>(x + (size_t)t0 * B_DIM * F_DIM, x_bf, n4);
        gemm_bt128<1><<<dim3(m / 128, H_DIM / 128), 256, 0, stream>>>(
            x_bf, W1b, b1, shr, F_DIM, H_DIM);
        gemm_bt128<0><<<dim3(m / 128, G_DIM / 128), 256, 0, stream>>>(
            shr, Wihp, bcomb, xg, H_DIM, G_DIM);

        lstm_seq<<<256, 256, 0, stream>>>(
            xg, Whhp, dones, Wv, hping, hpong, cbuf, hbuf, value, flags, vpart,
            t0, nt, (t0 == 0) ? 1 : 0);
    }
}

// Round 8
// 2963.918 us; speedup vs baseline: 1.5984x; 1.0835x over previous
//
#include <hip/hip_runtime.h>
#include <cstdint>
#include <cstddef>

#define T_DIM 128
#define B_DIM 256
#define F_DIM 512
#define H_DIM 1024
#define G_DIM 4096   // 4*H

typedef unsigned short u16;
typedef unsigned short u16x8 __attribute__((ext_vector_type(8)));
typedef unsigned short u16x4 __attribute__((ext_vector_type(4)));
typedef __bf16 bf16x8 __attribute__((ext_vector_type(8)));
typedef float f32x4 __attribute__((ext_vector_type(4)));

__device__ __forceinline__ float bf2f(u16 u) {
    union { unsigned v; float f; } x; x.v = ((unsigned)u) << 16; return x.f;
}
__device__ __forceinline__ u16 f2bf(float f) {
    union { float f; unsigned v; } x; x.f = f;
    return (u16)((x.v + 0x7fffu + ((x.v >> 16) & 1u)) >> 16);
}

__device__ __forceinline__ f32x4 mfma16(u16x8 a, u16x8 b, f32x4 c) {
    return __builtin_amdgcn_mfma_f32_16x16x32_bf16(
        __builtin_bit_cast(bf16x8, a), __builtin_bit_cast(bf16x8, b), c, 0, 0, 0);
}

__device__ __forceinline__ void gl_lds16(const void* g, void* s) {
    __builtin_amdgcn_global_load_lds(
        (const __attribute__((address_space(1))) void*)g,
        (__attribute__((address_space(3))) void*)s, 16, 0, 0);
}

__device__ __forceinline__ float sigm(float x) { return 1.0f / (1.0f + __expf(-x)); }
__device__ __forceinline__ float tanh_fast(float x) {
    float e = __expf(2.0f * x);
    return 1.0f - 2.0f / (e + 1.0f);
}

// ---------------------------------------------------------------------------
// GEMM: C[M,N] = epi(A[M,K] * B[N,K]^T + bias), bf16 in/out, f32 accum.
// 128x128 tile, BK=64, 4 waves (2x2). LDS-bounce epilogue for coalesced C.
// ---------------------------------------------------------------------------
template <int EPI>
__global__ __launch_bounds__(256) void gemm_bt128(
    const u16* __restrict__ A, const u16* __restrict__ B,
    const float* __restrict__ bias, u16* __restrict__ C, int K, int N) {
    __shared__ __align__(16) u16 smem[128 * 136];
    u16* lA = smem;
    u16* lB = smem + 8192;
    const int lane = threadIdx.x & 63;
    const int wave = threadIdx.x >> 6;
    const int wr = wave >> 1, wc = wave & 1;
    const int bm = blockIdx.x, bn = blockIdx.y;
    f32x4 acc[4][4] = {};
    const int srow = lane >> 3;
    const int scol = (lane & 7) * 8;
    const u16* Abase = A + (size_t)(bm * 128 + srow) * K + scol;
    const u16* Bbase = B + (size_t)(bn * 128 + srow) * K + scol;

    for (int k0 = 0; k0 < K; k0 += 64) {
#pragma unroll
        for (int j = 0; j < 4; ++j) {
            int chunk = wave * 4 + j;
            gl_lds16(Abase + (size_t)(chunk * 8) * K + k0, lA + chunk * 512);
            gl_lds16(Bbase + (size_t)(chunk * 8) * K + k0, lB + chunk * 512);
        }
        __syncthreads();
        const u16* pA = lA + (wr * 64 + (lane & 15)) * 64 + (lane >> 4) * 8;
        const u16* pB = lB + (wc * 64 + (lane & 15)) * 64 + (lane >> 4) * 8;
#pragma unroll
        for (int kk = 0; kk < 2; ++kk) {
            u16x8 a[4], b[4];
#pragma unroll
            for (int m = 0; m < 4; ++m) a[m] = *(const u16x8*)(pA + m * 1024 + kk * 32);
#pragma unroll
            for (int n = 0; n < 4; ++n) b[n] = *(const u16x8*)(pB + n * 1024 + kk * 32);
#pragma unroll
            for (int m = 0; m < 4; ++m)
#pragma unroll
                for (int n = 0; n < 4; ++n)
                    acc[m][n] = mfma16(a[m], b[n], acc[m][n]);
        }
        __syncthreads();
    }
#pragma unroll
    for (int n = 0; n < 4; ++n) {
        int cc = wc * 64 + n * 16 + (lane & 15);
        float bv = bias[bn * 128 + cc];
#pragma unroll
        for (int m = 0; m < 4; ++m) {
            int rr = wr * 64 + m * 16 + ((lane >> 4) * 4);
#pragma unroll
            for (int i = 0; i < 4; ++i) {
                float v = acc[m][n][i] + bv;
                if (EPI == 1) v = (v >= 0.0f) ? v : 0.01f * v;
                smem[(rr + i) * 136 + cc] = f2bf(v);
            }
        }
    }
    __syncthreads();
#pragma unroll
    for (int p = 0; p < 8; ++p) {
        int rr = p * 16 + wave * 4 + (lane >> 4);
        int cc = (lane & 15) * 8;
        u16x8 v = *(const u16x8*)(smem + rr * 136 + cc);
        *(u16x8*)(C + (size_t)(bm * 128 + rr) * N + bn * 128 + cc) = v;
    }
}

// ---------------------------------------------------------------------------
// Persistent LSTM chunk kernel. Grid 256 wgs x 256 thr.
// wg (bm = bid&3, bn = bid>>2): batch rows [bm*64,+64), gate cols [bn*64,+64).
// Wave w owns gate cols [bn*64 + w*16, +16): breg = 32 frags = 128 VGPRs.
// Sync: per-wg release-store flag; consumers RELAXED-spin (sc1 read-through,
// no cache maintenance) then ONE acquire load (single buffer_inv per step).
// R7's acquire-in-loop emitted buffer_inv per poll iteration -> L2 wiped
// continuously across all 256 CUs; that was the ~21us/step floor.
// ---------------------------------------------------------------------------

// Stage one [64 rows x 512B] K-chunk kc of a row-major [64][2048B] panel.
// LDS: row-major [64][512B], content swizzled: LDS(r,cb)=G(r,cb^((r&7)<<4)).
__device__ __forceinline__ void stage_chunk(const char* panel, char* buf, int kc,
                                            int wave, int lane) {
#pragma unroll
    for (int j = 0; j < 8; ++j) {
        int hr = wave * 8 + j;               // half-row pair index
        int r = hr * 2 + (lane >> 5);
        int sc = ((lane & 31) * 16) ^ ((r & 7) << 4);
        gl_lds16(panel + (size_t)r * 2048 + kc * 512 + sc, buf + (size_t)hr * 1024);
    }
}

__global__ __launch_bounds__(256, 1) void lstm_seq(
    const u16* __restrict__ xg, const u16* __restrict__ Whh,
    const int* __restrict__ dones, const float* __restrict__ Wv,
    u16* __restrict__ h0, u16* __restrict__ h1,
    float* __restrict__ cbuf, float* __restrict__ hbuf,
    float* __restrict__ value, int* __restrict__ flags,
    float* __restrict__ vpartial, int t0, int nt, int first) {
    __shared__ __align__(16) char sm[65536];   // 2 x 32KB chunk buffers; lepi reuses
    float* lepi = (float*)sm;
    const int tid = threadIdx.x;
    const int lane = tid & 63, wave = tid >> 6;
    const int bm = blockIdx.x & 3, bn = blockIdx.x >> 2;   // XCD-pair locality per bm
    const int sw = (lane & 7) << 4;

    // ---- Whh panel: wave w holds gate cols [w*16,+16), all K -> 128 VGPRs ----
    u16x8 breg[32];
    {
        const char* wp = (const char*)(Whh + (size_t)(bn * 64) * H_DIM);
        const int rlb = wave * 16 + (lane & 15);
#pragma unroll
        for (int kc = 0; kc < 4; ++kc) {
            char* buf = sm + (kc & 1) * 32768;
            stage_chunk(wp, buf, kc, wave, lane);
            __syncthreads();
#pragma unroll
            for (int s2 = 0; s2 < 8; ++s2) {
                int kb2 = s2 * 64 + (lane >> 4) * 16;
                breg[kc * 8 + s2] = *(const u16x8*)(buf + rlb * 512 + (kb2 ^ sw));
            }
            __syncthreads();
        }
    }

    // ---- per-thread epilogue state ----
    const int r = tid & 63;
    const int ublk = tid >> 6;
    const int bg = bm * 64 + r;
    const int ucol = bn * 16 + ublk * 4;
    float wv[4], c[4];
#pragma unroll
    for (int uu = 0; uu < 4; ++uu) wv[uu] = Wv[ucol + uu];
    if (first) {
        c[0] = c[1] = c[2] = c[3] = 0.0f;
    } else {
        float4 cv = *(const float4*)(cbuf + (size_t)bg * H_DIM + ucol);
        c[0] = cv.x; c[1] = cv.y; c[2] = cv.z; c[3] = cv.w;
    }

    for (int tt = 0; tt < nt; ++tt) {
        const int t = t0 + tt;
        const u16* hin = (t & 1) ? h1 : h0;
        u16* hout = (t & 1) ? h0 : h1;
        const char* hp = (const char*)(hin + (size_t)(bm * 64) * H_DIM);

        // step-constant data: load BEFORE the poll (independent of flags)
        const int done = dones[t * B_DIM + bg];
        u16x4 xv[4];
#pragma unroll
        for (int uu = 0; uu < 4; ++uu)
            xv[uu] = *(const u16x4*)(xg + (size_t)tt * B_DIM * G_DIM +
                                     (size_t)bg * G_DIM + bn * 64 + (ublk * 4 + uu) * 4);

        // ---- poll: RELAXED spin (no inv), then ONE acquire (one inv/step) ----
        if (t > 0 && tid < 64) {
            while (__hip_atomic_load(&flags[bm * 64 + tid], __ATOMIC_RELAXED,
                                     __HIP_MEMORY_SCOPE_AGENT) < t)
                __builtin_amdgcn_s_sleep(1);
            (void)__hip_atomic_load(&flags[bm * 64 + tid], __ATOMIC_ACQUIRE,
                                    __HIP_MEMORY_SCOPE_AGENT);
        }
        __syncthreads();

        // ---- stage chunk 0; value(t-1) reduce overlaps its latency ----
        stage_chunk(hp, sm, 0, wave, lane);
        if (t > 0 && tid < 64) {
            float4 v4 = *(const float4*)(vpartial + (size_t)((t - 1) & 1) * 65536 +
                                         (size_t)(bm * 64 + bn) * 256 + lane * 4);
            float s = v4.x + v4.y + v4.z + v4.w;
#pragma unroll
            for (int m2 = 32; m2 >= 1; m2 >>= 1) s += __shfl_xor(s, m2);
            if (tid == 0) value[(t - 1) * B_DIM + bm * 64 + bn] += s;
        }
        __syncthreads();

        // ---- K-chunked, double-buffered MFMA: acc[m] = rows m*16.., cols wave*16 ----
        f32x4 acc[4] = {};
#pragma unroll
        for (int kc = 0; kc < 4; ++kc) {
            char* buf = sm + (kc & 1) * 32768;
            if (kc < 3) stage_chunk(hp, sm + ((kc + 1) & 1) * 32768, kc + 1, wave, lane);
#pragma unroll
            for (int s2 = 0; s2 < 8; ++s2) {
                int kb2 = s2 * 64 + (lane >> 4) * 16;
#pragma unroll
                for (int m = 0; m < 4; ++m) {
                    u16x8 a = *(const u16x8*)(buf + (m * 16 + (lane & 15)) * 512 + (kb2 ^ sw));
                    acc[m] = mfma16(a, breg[kc * 8 + s2], acc[m]);
                }
            }
            __syncthreads();
        }

        // ---- scatter gate pre-activations (f32) into lepi ----
#pragma unroll
        for (int m = 0; m < 4; ++m)
#pragma unroll
            for (int i = 0; i < 4; ++i)
                lepi[(m * 16 + (lane >> 4) * 4 + i) * 65 + wave * 16 + (lane & 15)] = acc[m][i];
        __syncthreads();

        // ---- gate math: thread = (batch row r, 4 units) ----
        const float mb = (done == 0) ? 1.0f : 0.0f;
        float vpart = 0.0f;
        u16x4 hb;
        float hf[4];
#pragma unroll
        for (int uu = 0; uu < 4; ++uu) {
            const float* gp = &lepi[r * 65 + (ublk * 4 + uu) * 4];
            float gi = bf2f(xv[uu][0]) + mb * gp[0];
            float gf = bf2f(xv[uu][1]) + mb * gp[1];
            float gg = bf2f(xv[uu][2]) + mb * gp[2];
            float go = bf2f(xv[uu][3]) + mb * gp[3];
            float i_ = sigm(gi), f_ = sigm(gf), g_ = tanh_fast(gg), o_ = sigm(go);
            float cn = f_ * (mb * c[uu]) + i_ * g_;
            float hn = o_ * tanh_fast(cn);
            c[uu] = cn; hf[uu] = hn;
            hb[uu] = f2bf(hn);
            float lr = (hn >= 0.0f) ? hn : 0.01f * hn;
            vpart += lr * wv[uu];
        }
        *(u16x4*)(hout + (size_t)bg * H_DIM + ucol) = hb;
        if (t == T_DIM - 1)
            *(float4*)(hbuf + (size_t)bg * H_DIM + ucol) = make_float4(hf[0], hf[1], hf[2], hf[3]);
        vpartial[(size_t)(t & 1) * 65536 + (size_t)bg * 256 + bn * 4 + ublk] = vpart;

        // ---- release: syncthreads drains all waves' stores to L2, then one
        //      release-store (wbl2) publishes them + the flag. ----
        __syncthreads();
        if (tid == 0)
            __hip_atomic_store(&flags[bm * 64 + bn], t + 1, __ATOMIC_RELEASE,
                               __HIP_MEMORY_SCOPE_AGENT);
    }
    *(float4*)(cbuf + (size_t)bg * H_DIM + ucol) = make_float4(c[0], c[1], c[2], c[3]);

    // ---- final value row (t = T-1): wait for all group wgs (relaxed spin +
    //      one acquire), then reduce. ----
    if (t0 + nt == T_DIM && tid < 64) {
        while (__hip_atomic_load(&flags[bm * 64 + tid], __ATOMIC_RELAXED,
                                 __HIP_MEMORY_SCOPE_AGENT) < T_DIM)
            __builtin_amdgcn_s_sleep(1);
        (void)__hip_atomic_load(&flags[bm * 64 + tid], __ATOMIC_ACQUIRE,
                                __HIP_MEMORY_SCOPE_AGENT);
        float4 v4 = *(const float4*)(vpartial + (size_t)((T_DIM - 1) & 1) * 65536 +
                                     (size_t)(bm * 64 + bn) * 256 + lane * 4);
        float s = v4.x + v4.y + v4.z + v4.w;
#pragma unroll
        for (int m2 = 32; m2 >= 1; m2 >>= 1) s += __shfl_xor(s, m2);
        if (tid == 0) value[(T_DIM - 1) * B_DIM + bm * 64 + bn] += s;
    }
}

// ---------------------------------------------------------------------------
__global__ void k_cast_bf16(const float* __restrict__ in, u16* __restrict__ out, int n4) {
    int i = blockIdx.x * 256 + threadIdx.x;
    if (i < n4) {
        float4 v = *(const float4*)(in + (size_t)i * 4);
        u16x4 o;
        o[0] = f2bf(v.x); o[1] = f2bf(v.y); o[2] = f2bf(v.z); o[3] = f2bf(v.w);
        *(u16x4*)(out + (size_t)i * 4) = o;
    }
}

__global__ void k_permute_w(const float* __restrict__ W, u16* __restrict__ Wp) {
    int row = blockIdx.x;
    int rin = (row & 3) * H_DIM + (row >> 2);
    int c = threadIdx.x * 4;
    float4 v = *(const float4*)(W + (size_t)rin * H_DIM + c);
    u16x4 o;
    o[0] = f2bf(v.x); o[1] = f2bf(v.y); o[2] = f2bf(v.z); o[3] = f2bf(v.w);
    *(u16x4*)(Wp + (size_t)row * H_DIM + c) = o;
}

__global__ void k_prep_bias(const float* __restrict__ b_ih, const float* __restrict__ b_hh,
                            float* __restrict__ bc) {
    int i = blockIdx.x * 256 + threadIdx.x;
    int n = i >> 2, q = i & 3;
    bc[i] = b_ih[q * H_DIM + n] + b_hh[q * H_DIM + n];
}

__global__ void k_init(float* __restrict__ value, const float* __restrict__ bv,
                       u16* __restrict__ h0, int* __restrict__ flags) {
    int i = blockIdx.x * 256 + threadIdx.x;
    if (i < B_DIM * H_DIM) h0[i] = 0;
    if (i < T_DIM * B_DIM) value[i] = *bv;
    if (i < 256) flags[i] = 0;
}

extern "C" void kernel_launch(void* const* d_in, const int* in_sizes, int n_in,
                              void* d_out, int out_size, void* d_ws, size_t ws_size,
                              hipStream_t stream) {
    const float* x     = (const float*)d_in[0];
    const int*   dones = (const int*)d_in[1];
    const float* W1    = (const float*)d_in[2];
    const float* b1    = (const float*)d_in[3];
    const float* W_ih  = (const float*)d_in[4];
    const float* W_hh  = (const float*)d_in[5];
    const float* b_ih  = (const float*)d_in[6];
    const float* b_hh  = (const float*)d_in[7];
    const float* Wv    = (const float*)d_in[8];
    const float* bv    = (const float*)d_in[9];

    float* out   = (float*)d_out;
    float* value = out;                          // [T*B]
    float* hbuf  = out + (size_t)T_DIM * B_DIM;  // h_T [B*H] f32
    float* cbuf  = hbuf + (size_t)B_DIM * H_DIM; // c_T [B*H] f32

    const size_t per_nt = (size_t)(F_DIM + H_DIM + G_DIM) * B_DIM * 2;
    const size_t fixed = (size_t)H_DIM * F_DIM * 2 + 2 * (size_t)G_DIM * H_DIM * 2 +
                         G_DIM * 4 + 2 * (size_t)B_DIM * H_DIM * 2 +
                         2 * 65536 * 4 + 8192;
    int nt = 2;
    for (int cand = 16; cand >= 2; cand >>= 1)
        if (fixed + (size_t)cand * per_nt + 65536 <= ws_size) { nt = cand; break; }

    char* ws = (char*)d_ws;
    size_t off = 0;
    auto alloc = [&](size_t bytes) {
        void* p = ws + off;
        off = (off + bytes + 255) & ~(size_t)255;
        return p;
    };
    u16*   x_bf   = (u16*)alloc((size_t)nt * B_DIM * F_DIM * 2);
    u16*   shr    = (u16*)alloc((size_t)nt * B_DIM * H_DIM * 2);
    u16*   xg     = (u16*)alloc((size_t)nt * B_DIM * G_DIM * 2);
    u16*   W1b    = (u16*)alloc((size_t)H_DIM * F_DIM * 2);
    u16*   Wihp   = (u16*)alloc((size_t)G_DIM * H_DIM * 2);
    u16*   Whhp   = (u16*)alloc((size_t)G_DIM * H_DIM * 2);
    float* bcomb  = (float*)alloc((size_t)G_DIM * 4);
    u16*   hping  = (u16*)alloc((size_t)B_DIM * H_DIM * 2);
    u16*   hpong  = (u16*)alloc((size_t)B_DIM * H_DIM * 2);
    int*   flags  = (int*)alloc(256 * 4);
    float* vpart  = (float*)alloc(2 * 65536 * 4);

    // ---- weight prep ----
    k_cast_bf16<<<(H_DIM * F_DIM / 4) / 256, 256, 0, stream>>>(W1, W1b, H_DIM * F_DIM / 4);
    k_permute_w<<<G_DIM, 256, 0, stream>>>(W_ih, Wihp);
    k_permute_w<<<G_DIM, 256, 0, stream>>>(W_hh, Whhp);
    k_prep_bias<<<G_DIM / 256, 256, 0, stream>>>(b_ih, b_hh, bcomb);
    k_init<<<(B_DIM * H_DIM) / 256, 256, 0, stream>>>(value, bv, hping, flags);

    for (int t0 = 0; t0 < T_DIM; t0 += nt) {
        int m = nt * B_DIM;
        int n4 = m * F_DIM / 4;
        k_cast_bf16<<<n4 / 256, 256, 0, stream>>>(x + (size_t)t0 * B_DIM * F_DIM, x_bf, n4);
        gemm_bt128<1><<<dim3(m / 128, H_DIM / 128), 256, 0, stream>>>(
            x_bf, W1b, b1, shr, F_DIM, H_DIM);
        gemm_bt128<0><<<dim3(m / 128, G_DIM / 128), 256, 0, stream>>>(
            shr, Wihp, bcomb, xg, H_DIM, G_DIM);

        lstm_seq<<<256, 256, 0, stream>>>(
            xg, Whhp, dones, Wv, hping, hpong, cbuf, hbuf, value, flags, vpart,
            t0, nt, (t0 == 0) ? 1 : 0);
    }
}

// Round 9
// 1727.162 us; speedup vs baseline: 2.7430x; 1.7161x over previous
//
#include <hip/hip_runtime.h>
#include <cstdint>
#include <cstddef>

#define T_DIM 128
#define B_DIM 256
#define F_DIM 512
#define H_DIM 1024
#define G_DIM 4096   // 4*H

typedef unsigned short u16;
typedef unsigned short u16x8 __attribute__((ext_vector_type(8)));
typedef unsigned short u16x4 __attribute__((ext_vector_type(4)));
typedef __bf16 bf16x8 __attribute__((ext_vector_type(8)));
typedef float f32x4 __attribute__((ext_vector_type(4)));

__device__ __forceinline__ float bf2f(u16 u) {
    union { unsigned v; float f; } x; x.v = ((unsigned)u) << 16; return x.f;
}
__device__ __forceinline__ u16 f2bf(float f) {
    union { float f; unsigned v; } x; x.f = f;
    return (u16)((x.v + 0x7fffu + ((x.v >> 16) & 1u)) >> 16);
}

__device__ __forceinline__ f32x4 mfma16(u16x8 a, u16x8 b, f32x4 c) {
    return __builtin_amdgcn_mfma_f32_16x16x32_bf16(
        __builtin_bit_cast(bf16x8, a), __builtin_bit_cast(bf16x8, b), c, 0, 0, 0);
}

// AUX = cache-policy immediate (LLVM CPol): SC0=1, SC1=16. 17 = coherent (L3) read.
template <int AUX>
__device__ __forceinline__ void gl_lds16(const void* g, void* s) {
    __builtin_amdgcn_global_load_lds(
        (const __attribute__((address_space(1))) void*)g,
        (__attribute__((address_space(3))) void*)s, 16, 0, AUX);
}

__device__ __forceinline__ float sigm(float x) { return 1.0f / (1.0f + __expf(-x)); }
__device__ __forceinline__ float tanh_fast(float x) {
    float e = __expf(2.0f * x);
    return 1.0f - 2.0f / (e + 1.0f);
}

// ---------------------------------------------------------------------------
// GEMM: C[M,N] = epi(A[M,K] * B[N,K]^T + bias), bf16 in/out, f32 accum.
// 128x128 tile, BK=64, 4 waves (2x2). LDS-bounce epilogue for coalesced C.
// ---------------------------------------------------------------------------
template <int EPI>
__global__ __launch_bounds__(256) void gemm_bt128(
    const u16* __restrict__ A, const u16* __restrict__ B,
    const float* __restrict__ bias, u16* __restrict__ C, int K, int N) {
    __shared__ __align__(16) u16 smem[128 * 136];
    u16* lA = smem;
    u16* lB = smem + 8192;
    const int lane = threadIdx.x & 63;
    const int wave = threadIdx.x >> 6;
    const int wr = wave >> 1, wc = wave & 1;
    const int bm = blockIdx.x, bn = blockIdx.y;
    f32x4 acc[4][4] = {};
    const int srow = lane >> 3;
    const int scol = (lane & 7) * 8;
    const u16* Abase = A + (size_t)(bm * 128 + srow) * K + scol;
    const u16* Bbase = B + (size_t)(bn * 128 + srow) * K + scol;

    for (int k0 = 0; k0 < K; k0 += 64) {
#pragma unroll
        for (int j = 0; j < 4; ++j) {
            int chunk = wave * 4 + j;
            gl_lds16<0>(Abase + (size_t)(chunk * 8) * K + k0, lA + chunk * 512);
            gl_lds16<0>(Bbase + (size_t)(chunk * 8) * K + k0, lB + chunk * 512);
        }
        __syncthreads();
        const u16* pA = lA + (wr * 64 + (lane & 15)) * 64 + (lane >> 4) * 8;
        const u16* pB = lB + (wc * 64 + (lane & 15)) * 64 + (lane >> 4) * 8;
#pragma unroll
        for (int kk = 0; kk < 2; ++kk) {
            u16x8 a[4], b[4];
#pragma unroll
            for (int m = 0; m < 4; ++m) a[m] = *(const u16x8*)(pA + m * 1024 + kk * 32);
#pragma unroll
            for (int n = 0; n < 4; ++n) b[n] = *(const u16x8*)(pB + n * 1024 + kk * 32);
#pragma unroll
            for (int m = 0; m < 4; ++m)
#pragma unroll
                for (int n = 0; n < 4; ++n)
                    acc[m][n] = mfma16(a[m], b[n], acc[m][n]);
        }
        __syncthreads();
    }
#pragma unroll
    for (int n = 0; n < 4; ++n) {
        int cc = wc * 64 + n * 16 + (lane & 15);
        float bv = bias[bn * 128 + cc];
#pragma unroll
        for (int m = 0; m < 4; ++m) {
            int rr = wr * 64 + m * 16 + ((lane >> 4) * 4);
#pragma unroll
            for (int i = 0; i < 4; ++i) {
                float v = acc[m][n][i] + bv;
                if (EPI == 1) v = (v >= 0.0f) ? v : 0.01f * v;
                smem[(rr + i) * 136 + cc] = f2bf(v);
            }
        }
    }
    __syncthreads();
#pragma unroll
    for (int p = 0; p < 8; ++p) {
        int rr = p * 16 + wave * 4 + (lane >> 4);
        int cc = (lane & 15) * 8;
        u16x8 v = *(const u16x8*)(smem + rr * 136 + cc);
        *(u16x8*)(C + (size_t)(bm * 128 + rr) * N + bn * 128 + cc) = v;
    }
}

// ---------------------------------------------------------------------------
// Persistent LSTM chunk kernel. Grid 256 wgs x 256 thr.
// wg (bm = bid&3, bn = bid>>2): batch rows [bm*64,+64), gate cols [bn*64,+64).
// Wave w owns gate cols [bn*64 + w*16, +16): breg = 32 frags = 128 VGPRs.
// Sync design (R9): ZERO cache-maintenance in the loop. All cross-wg data
// (h, vpartial, flags) moves through the L3 coherent point:
//   producers : relaxed agent atomic stores (sc1 write-through, no dirty L2)
//   ordering  : __syncthreads (per-wave vmcnt(0) drain) before flag store
//   consumers : relaxed poll; h staged via global_load_lds aux=SC0|SC1 (17)
// R8's release-wbl2 (32/XCD/step) + acquire-inv (32/XCD/step) was the floor.
// ---------------------------------------------------------------------------

// Stage one [64 rows x 512B] K-chunk kc of a row-major [64][2048B] panel.
// LDS: row-major [64][512B], content swizzled: LDS(r,cb)=G(r,cb^((r&7)<<4)).
template <int AUX>
__device__ __forceinline__ void stage_chunk(const char* panel, char* buf, int kc,
                                            int wave, int lane) {
#pragma unroll
    for (int j = 0; j < 8; ++j) {
        int hr = wave * 8 + j;               // half-row pair index
        int r = hr * 2 + (lane >> 5);
        int sc = ((lane & 31) * 16) ^ ((r & 7) << 4);
        gl_lds16<AUX>(panel + (size_t)r * 2048 + kc * 512 + sc, buf + (size_t)hr * 1024);
    }
}

__global__ __launch_bounds__(256, 1) void lstm_seq(
    const u16* __restrict__ xg, const u16* __restrict__ Whh,
    const int* __restrict__ dones, const float* __restrict__ Wv,
    u16* __restrict__ h0, u16* __restrict__ h1,
    float* __restrict__ cbuf, float* __restrict__ hbuf,
    float* __restrict__ value, int* __restrict__ flags,
    float* __restrict__ vpartial, int t0, int nt, int first) {
    __shared__ __align__(16) char sm[65536];   // 2 x 32KB chunk buffers; lepi reuses
    float* lepi = (float*)sm;
    const int tid = threadIdx.x;
    const int lane = tid & 63, wave = tid >> 6;
    const int bm = blockIdx.x & 3, bn = blockIdx.x >> 2;   // each XCD hosts one bm group
    const int sw = (lane & 7) << 4;

    // ---- Whh panel: wave w holds gate cols [w*16,+16), all K -> 128 VGPRs ----
    u16x8 breg[32];
    {
        const char* wp = (const char*)(Whh + (size_t)(bn * 64) * H_DIM);
        const int rlb = wave * 16 + (lane & 15);
#pragma unroll
        for (int kc = 0; kc < 4; ++kc) {
            char* buf = sm + (kc & 1) * 32768;
            stage_chunk<0>(wp, buf, kc, wave, lane);
            __syncthreads();
#pragma unroll
            for (int s2 = 0; s2 < 8; ++s2) {
                int kb2 = s2 * 64 + (lane >> 4) * 16;
                breg[kc * 8 + s2] = *(const u16x8*)(buf + rlb * 512 + (kb2 ^ sw));
            }
            __syncthreads();
        }
    }

    // ---- per-thread epilogue state ----
    const int r = tid & 63;
    const int ublk = tid >> 6;
    const int bg = bm * 64 + r;
    const int ucol = bn * 16 + ublk * 4;
    float wv[4], c[4];
#pragma unroll
    for (int uu = 0; uu < 4; ++uu) wv[uu] = Wv[ucol + uu];
    if (first) {
        c[0] = c[1] = c[2] = c[3] = 0.0f;
    } else {
        float4 cv = *(const float4*)(cbuf + (size_t)bg * H_DIM + ucol);
        c[0] = cv.x; c[1] = cv.y; c[2] = cv.z; c[3] = cv.w;
    }

    for (int tt = 0; tt < nt; ++tt) {
        const int t = t0 + tt;
        const u16* hin = (t & 1) ? h1 : h0;
        u16* hout = (t & 1) ? h0 : h1;
        const char* hp = (const char*)(hin + (size_t)(bm * 64) * H_DIM);

        // step-constant data: load BEFORE the poll (independent of flags)
        const int done = dones[t * B_DIM + bg];
        u16x4 xv[4];
#pragma unroll
        for (int uu = 0; uu < 4; ++uu)
            xv[uu] = *(const u16x4*)(xg + (size_t)tt * B_DIM * G_DIM +
                                     (size_t)bg * G_DIM + bn * 64 + (ublk * 4 + uu) * 4);

        // ---- poll: relaxed coherent loads only (no inv, no fence) ----
        if (t > 0 && tid < 64) {
            while (__hip_atomic_load(&flags[bm * 64 + tid], __ATOMIC_RELAXED,
                                     __HIP_MEMORY_SCOPE_AGENT) < t)
                __builtin_amdgcn_s_sleep(1);
        }
        __syncthreads();   // compiler + exec barrier: staging cannot start early

        // ---- stage chunk 0 (coherent reads); value(t-1) reduce overlaps ----
        stage_chunk<17>(hp, sm, 0, wave, lane);
        if (t > 0 && tid < 64) {
            const float* vp = vpartial + (size_t)((t - 1) & 1) * 65536 +
                              (size_t)(bm * 64 + bn) * 256 + lane * 4;
            union { unsigned long long u; float f[2]; } ua, ub;
            ua.u = __hip_atomic_load((const unsigned long long*)vp, __ATOMIC_RELAXED,
                                     __HIP_MEMORY_SCOPE_AGENT);
            ub.u = __hip_atomic_load((const unsigned long long*)(vp + 2), __ATOMIC_RELAXED,
                                     __HIP_MEMORY_SCOPE_AGENT);
            float s = ua.f[0] + ua.f[1] + ub.f[0] + ub.f[1];
#pragma unroll
            for (int m2 = 32; m2 >= 1; m2 >>= 1) s += __shfl_xor(s, m2);
            if (tid == 0) value[(t - 1) * B_DIM + bm * 64 + bn] += s;
        }
        __syncthreads();

        // ---- K-chunked, double-buffered MFMA: acc[m] = rows m*16.., cols wave*16 ----
        f32x4 acc[4] = {};
#pragma unroll
        for (int kc = 0; kc < 4; ++kc) {
            char* buf = sm + (kc & 1) * 32768;
            if (kc < 3) stage_chunk<17>(hp, sm + ((kc + 1) & 1) * 32768, kc + 1, wave, lane);
#pragma unroll
            for (int s2 = 0; s2 < 8; ++s2) {
                int kb2 = s2 * 64 + (lane >> 4) * 16;
#pragma unroll
                for (int m = 0; m < 4; ++m) {
                    u16x8 a = *(const u16x8*)(buf + (m * 16 + (lane & 15)) * 512 + (kb2 ^ sw));
                    acc[m] = mfma16(a, breg[kc * 8 + s2], acc[m]);
                }
            }
            __syncthreads();
        }

        // ---- scatter gate pre-activations (f32) into lepi ----
#pragma unroll
        for (int m = 0; m < 4; ++m)
#pragma unroll
            for (int i = 0; i < 4; ++i)
                lepi[(m * 16 + (lane >> 4) * 4 + i) * 65 + wave * 16 + (lane & 15)] = acc[m][i];
        __syncthreads();

        // ---- gate math: thread = (batch row r, 4 units) ----
        const float mb = (done == 0) ? 1.0f : 0.0f;
        float vpart = 0.0f;
        u16x4 hb;
        float hf[4];
#pragma unroll
        for (int uu = 0; uu < 4; ++uu) {
            const float* gp = &lepi[r * 65 + (ublk * 4 + uu) * 4];
            float gi = bf2f(xv[uu][0]) + mb * gp[0];
            float gf = bf2f(xv[uu][1]) + mb * gp[1];
            float gg = bf2f(xv[uu][2]) + mb * gp[2];
            float go = bf2f(xv[uu][3]) + mb * gp[3];
            float i_ = sigm(gi), f_ = sigm(gf), g_ = tanh_fast(gg), o_ = sigm(go);
            float cn = f_ * (mb * c[uu]) + i_ * g_;
            float hn = o_ * tanh_fast(cn);
            c[uu] = cn; hf[uu] = hn;
            hb[uu] = f2bf(hn);
            float lr = (hn >= 0.0f) ? hn : 0.01f * hn;
            vpart += lr * wv[uu];
        }
        // h + vpartial: relaxed agent atomic stores -> write-through to L3, no dirty L2
        __hip_atomic_store((unsigned long long*)(hout + (size_t)bg * H_DIM + ucol),
                           __builtin_bit_cast(unsigned long long, hb),
                           __ATOMIC_RELAXED, __HIP_MEMORY_SCOPE_AGENT);
        if (t == T_DIM - 1)
            *(float4*)(hbuf + (size_t)bg * H_DIM + ucol) = make_float4(hf[0], hf[1], hf[2], hf[3]);
        __hip_atomic_store(&vpartial[(size_t)(t & 1) * 65536 + (size_t)bg * 256 + bn * 4 + ublk],
                           vpart, __ATOMIC_RELAXED, __HIP_MEMORY_SCOPE_AGENT);

        // ---- publish: syncthreads drains every wave's vmcnt(0) -> all coherent
        //      stores complete at L3; then one relaxed flag store. No wbl2. ----
        __syncthreads();
        if (tid == 0)
            __hip_atomic_store(&flags[bm * 64 + bn], t + 1, __ATOMIC_RELAXED,
                               __HIP_MEMORY_SCOPE_AGENT);
    }
    *(float4*)(cbuf + (size_t)bg * H_DIM + ucol) = make_float4(c[0], c[1], c[2], c[3]);

    // ---- final value row (t = T-1): poll all group wgs, then coherent reduce ----
    if (t0 + nt == T_DIM && tid < 64) {
        while (__hip_atomic_load(&flags[bm * 64 + tid], __ATOMIC_RELAXED,
                                 __HIP_MEMORY_SCOPE_AGENT) < T_DIM)
            __builtin_amdgcn_s_sleep(1);
        const float* vp = vpartial + (size_t)((T_DIM - 1) & 1) * 65536 +
                          (size_t)(bm * 64 + bn) * 256 + lane * 4;
        union { unsigned long long u; float f[2]; } ua, ub;
        ua.u = __hip_atomic_load((const unsigned long long*)vp, __ATOMIC_RELAXED,
                                 __HIP_MEMORY_SCOPE_AGENT);
        ub.u = __hip_atomic_load((const unsigned long long*)(vp + 2), __ATOMIC_RELAXED,
                                 __HIP_MEMORY_SCOPE_AGENT);
        float s = ua.f[0] + ua.f[1] + ub.f[0] + ub.f[1];
#pragma unroll
        for (int m2 = 32; m2 >= 1; m2 >>= 1) s += __shfl_xor(s, m2);
        if (tid == 0) value[(T_DIM - 1) * B_DIM + bm * 64 + bn] += s;
    }
}

// ---------------------------------------------------------------------------
__global__ void k_cast_bf16(const float* __restrict__ in, u16* __restrict__ out, int n4) {
    int i = blockIdx.x * 256 + threadIdx.x;
    if (i < n4) {
        float4 v = *(const float4*)(in + (size_t)i * 4);
        u16x4 o;
        o[0] = f2bf(v.x); o[1] = f2bf(v.y); o[2] = f2bf(v.z); o[3] = f2bf(v.w);
        *(u16x4*)(out + (size_t)i * 4) = o;
    }
}

__global__ void k_permute_w(const float* __restrict__ W, u16* __restrict__ Wp) {
    int row = blockIdx.x;
    int rin = (row & 3) * H_DIM + (row >> 2);
    int c = threadIdx.x * 4;
    float4 v = *(const float4*)(W + (size_t)rin * H_DIM + c);
    u16x4 o;
    o[0] = f2bf(v.x); o[1] = f2bf(v.y); o[2] = f2bf(v.z); o[3] = f2bf(v.w);
    *(u16x4*)(Wp + (size_t)row * H_DIM + c) = o;
}

__global__ void k_prep_bias(const float* __restrict__ b_ih, const float* __restrict__ b_hh,
                            float* __restrict__ bc) {
    int i = blockIdx.x * 256 + threadIdx.x;
    int n = i >> 2, q = i & 3;
    bc[i] = b_ih[q * H_DIM + n] + b_hh[q * H_DIM + n];
}

__global__ void k_init(float* __restrict__ value, const float* __restrict__ bv,
                       u16* __restrict__ h0, int* __restrict__ flags) {
    int i = blockIdx.x * 256 + threadIdx.x;
    if (i < B_DIM * H_DIM) h0[i] = 0;
    if (i < T_DIM * B_DIM) value[i] = *bv;
    if (i < 256) flags[i] = 0;
}

extern "C" void kernel_launch(void* const* d_in, const int* in_sizes, int n_in,
                              void* d_out, int out_size, void* d_ws, size_t ws_size,
                              hipStream_t stream) {
    const float* x     = (const float*)d_in[0];
    const int*   dones = (const int*)d_in[1];
    const float* W1    = (const float*)d_in[2];
    const float* b1    = (const float*)d_in[3];
    const float* W_ih  = (const float*)d_in[4];
    const float* W_hh  = (const float*)d_in[5];
    const float* b_ih  = (const float*)d_in[6];
    const float* b_hh  = (const float*)d_in[7];
    const float* Wv    = (const float*)d_in[8];
    const float* bv    = (const float*)d_in[9];

    float* out   = (float*)d_out;
    float* value = out;                          // [T*B]
    float* hbuf  = out + (size_t)T_DIM * B_DIM;  // h_T [B*H] f32
    float* cbuf  = hbuf + (size_t)B_DIM * H_DIM; // c_T [B*H] f32

    const size_t per_nt = (size_t)(F_DIM + H_DIM + G_DIM) * B_DIM * 2;
    const size_t fixed = (size_t)H_DIM * F_DIM * 2 + 2 * (size_t)G_DIM * H_DIM * 2 +
                         G_DIM * 4 + 2 * (size_t)B_DIM * H_DIM * 2 +
                         2 * 65536 * 4 + 8192;
    int nt = 2;
    for (int cand = 16; cand >= 2; cand >>= 1)
        if (fixed + (size_t)cand * per_nt + 65536 <= ws_size) { nt = cand; break; }

    char* ws = (char*)d_ws;
    size_t off = 0;
    auto alloc = [&](size_t bytes) {
        void* p = ws + off;
        off = (off + bytes + 255) & ~(size_t)255;
        return p;
    };
    u16*   x_bf   = (u16*)alloc((size_t)nt * B_DIM * F_DIM * 2);
    u16*   shr    = (u16*)alloc((size_t)nt * B_DIM * H_DIM * 2);
    u16*   xg     = (u16*)alloc((size_t)nt * B_DIM * G_DIM * 2);
    u16*   W1b    = (u16*)alloc((size_t)H_DIM * F_DIM * 2);
    u16*   Wihp   = (u16*)alloc((size_t)G_DIM * H_DIM * 2);
    u16*   Whhp   = (u16*)alloc((size_t)G_DIM * H_DIM * 2);
    float* bcomb  = (float*)alloc((size_t)G_DIM * 4);
    u16*   hping  = (u16*)alloc((size_t)B_DIM * H_DIM * 2);
    u16*   hpong  = (u16*)alloc((size_t)B_DIM * H_DIM * 2);
    int*   flags  = (int*)alloc(256 * 4);
    float* vpart  = (float*)alloc(2 * 65536 * 4);

    // ---- weight prep ----
    k_cast_bf16<<<(H_DIM * F_DIM / 4) / 256, 256, 0, stream>>>(W1, W1b, H_DIM * F_DIM / 4);
    k_permute_w<<<G_DIM, 256, 0, stream>>>(W_ih, Wihp);
    k_permute_w<<<G_DIM, 256, 0, stream>>>(W_hh, Whhp);
    k_prep_bias<<<G_DIM / 256, 256, 0, stream>>>(b_ih, b_hh, bcomb);
    k_init<<<(B_DIM * H_DIM) / 256, 256, 0, stream>>>(value, bv, hping, flags);

    for (int t0 = 0; t0 < T_DIM; t0 += nt) {
        int m = nt * B_DIM;
        int n4 = m * F_DIM / 4;
        k_cast_bf16<<<n4 / 256, 256, 0, stream>>>(x + (size_t)t0 * B_DIM * F_DIM, x_bf, n4);
        gemm_bt128<1><<<dim3(m / 128, H_DIM / 128), 256, 0, stream>>>(
            x_bf, W1b, b1, shr, F_DIM, H_DIM);
        gemm_bt128<0><<<dim3(m / 128, G_DIM / 128), 256, 0, stream>>>(
            shr, Wihp, bcomb, xg, H_DIM, G_DIM);

        lstm_seq<<<256, 256, 0, stream>>>(
            xg, Whhp, dones, Wv, hping, hpong, cbuf, hbuf, value, flags, vpart,
            t0, nt, (t0 == 0) ? 1 : 0);
    }
}